// Round 7
// baseline (664.906 us; speedup 1.0000x reference)
//
#include <hip/hip_runtime.h>

#define B_ROWS 65536
#define D_IN   1024
#define H1N    512
#define H2N    256

typedef _Float16 half8  __attribute__((ext_vector_type(8)));
typedef __fp16   fp16x2 __attribute__((ext_vector_type(2)));
typedef float    f32x4v __attribute__((ext_vector_type(4)));

// ---------------------------------------------------------------------------
// Transpose+split+PACK weights: W [Kd][Nd] fp32 -> fragment-major fp16 hi/lo.
// Packed unit (ks, nf, l): half8 = W[ks*32 + (l>>4)*8 + j][nf*16 + (l&15)],
// stored at ((ks*(Nd/16) + nf)*64 + l). A wave's b-frag load is then one
// fully-coalesced 1 KB global_load_dwordx4.
// ---------------------------------------------------------------------------
__global__ __launch_bounds__(256)
void splitw_pk(const float* __restrict__ W, half8* __restrict__ ph,
               half8* __restrict__ pl, int Kd, int Nd)
{
    __shared__ float tile[64][65];
    const int t = threadIdx.x;
    const int ntn = Nd >> 6;
    const int kt = blockIdx.x / ntn, nt = blockIdx.x % ntn;
    const int k0 = kt << 6, n0 = nt << 6;

    {
        int r = t >> 4, c4 = (t & 15) << 2;
        #pragma unroll
        for (int i = 0; i < 4; ++i) {
            float4 v = *(const float4*)(W + (size_t)(k0 + r + i * 16) * Nd + n0 + c4);
            tile[r + i*16][c4+0] = v.x; tile[r + i*16][c4+1] = v.y;
            tile[r + i*16][c4+2] = v.z; tile[r + i*16][c4+3] = v.w;
        }
    }
    __syncthreads();
    #pragma unroll
    for (int uu = 0; uu < 2; ++uu) {
        int u = t + uu * 256;
        int l = u & 63, nfl = (u >> 6) & 3, ksl = u >> 8;
        int col = nfl * 16 + (l & 15);
        int kb  = ksl * 32 + (l >> 4) * 8;
        union { fp16x2 h2[4]; half8 h8; } H, L;
        #pragma unroll
        for (int i = 0; i < 4; ++i) {
            float v0 = tile[kb + 2*i][col], v1 = tile[kb + 2*i + 1][col];
            float h0 = __int_as_float(__float_as_int(v0) & 0xFFFFE000);
            float h1 = __int_as_float(__float_as_int(v1) & 0xFFFFE000);
            H.h2[i] = __builtin_amdgcn_cvt_pkrtz(h0, h1);
            L.h2[i] = __builtin_amdgcn_cvt_pkrtz(v0 - h0, v1 - h1);
        }
        size_t idx = ((size_t)((kt*2 + ksl) * (Nd >> 4) + nt*4 + nfl)) * 64 + l;
        ph[idx] = H.h8;
        pl[idx] = L.h8;
    }
}

// ---------------------------------------------------------------------------
// Zero-LDS zero-barrier split-fp16 GEMM:
// C = [bnrelu?](A) @ B^T + bias, fused column-stat partials.
// Block 128x256, 4 waves 2x2, wave tile 64x128, mfma 16x16x32 f16,
// 3 products (hh, hl, lh). A fp32 direct global->reg (k-contiguous, split
// in-reg); B from packed fragment-major hi/lo (coalesced 1KB loads, L2-hot).
// No LDS staging, no K-loop barriers -> waves free-run, loads overlap MFMA.
// ---------------------------------------------------------------------------
template<int K, int NBn, bool BNRELU>
__global__ __launch_bounds__(256, 2)
void gemm_direct(const float* __restrict__ Ain, const half8* __restrict__ Bph,
                 const half8* __restrict__ Bpl, const float* __restrict__ bias,
                 const float2* __restrict__ scsh, float* __restrict__ Cout,
                 float2* __restrict__ statp)
{
    constexpr int N  = NBn * 256;
    constexpr int NS = K / 32;
    constexpr int NF = N / 16;
    __shared__ float2 scl[BNRELU ? K : 8];
    __shared__ float2 sred[256];

    const int tid = threadIdx.x;
    const int l = tid & 63;
    const int w = tid >> 6;
    const int wr = w >> 1, wc = w & 1;

    constexpr int NWG = NBn * 512;
    const int bid = blockIdx.x;
    const int L = (bid & 7) * (NWG >> 3) + (bid >> 3);   // bijective XCD swizzle
    const int mb = L / NBn, nbi = L % NBn;
    const int m0 = mb << 7, n0 = nbi << 8;

    if constexpr (BNRELU) {
        for (int i = tid; i < K; i += 256) scl[i] = scsh[i];
        __syncthreads();
    }
    (void)scsh;

    const int kg = l >> 4;                                // 0..3 k-subchunk
    const float* aptr = Ain + (size_t)(m0 + wr * 64 + (l & 15)) * K + kg * 8;
    const int nfb = (n0 >> 4) + wc * 8;                   // wave's frag base

    f32x4v acc[4][8] = {};

    #pragma unroll 2
    for (int ks = 0; ks < NS; ++ks) {
        float2 ss[8];
        if constexpr (BNRELU) {
            const float2* sp = scl + ks * 32 + kg * 8;    // GLOBAL k indexing
            #pragma unroll
            for (int i = 0; i < 8; ++i) ss[i] = sp[i];
        }
        half8 ah[4], al[4];
        #pragma unroll
        for (int mm = 0; mm < 4; ++mm) {
            const float* p = aptr + (size_t)mm * 16 * K + ks * 32;
            f32x4v va = *(const f32x4v*)p;
            f32x4v vb = *(const f32x4v*)(p + 4);
            if constexpr (BNRELU) {
                #pragma unroll
                for (int e = 0; e < 4; ++e) {
                    va[e] = fmaxf(fmaf(va[e], ss[e].x,     ss[e].y),     0.f);
                    vb[e] = fmaxf(fmaf(vb[e], ss[4 + e].x, ss[4 + e].y), 0.f);
                }
            }
            union { fp16x2 h2[4]; half8 h8; } H, Lo;
            #pragma unroll
            for (int i = 0; i < 4; ++i) {
                float a0 = (i < 2) ? va[2*i]     : vb[2*(i-2)];
                float a1 = (i < 2) ? va[2*i + 1] : vb[2*(i-2) + 1];
                float h0 = __int_as_float(__float_as_int(a0) & 0xFFFFE000);
                float h1 = __int_as_float(__float_as_int(a1) & 0xFFFFE000);
                H.h2[i]  = __builtin_amdgcn_cvt_pkrtz(h0, h1);
                Lo.h2[i] = __builtin_amdgcn_cvt_pkrtz(a0 - h0, a1 - h1);
            }
            ah[mm] = H.h8; al[mm] = Lo.h8;
        }
        #pragma unroll
        for (int nh = 0; nh < 2; ++nh) {
            half8 bh[4], bl[4];
            #pragma unroll
            for (int nf = 0; nf < 4; ++nf) {
                size_t idx = ((size_t)ks * NF + nfb + nh * 4 + nf) * 64 + l;
                bh[nf] = Bph[idx];
                bl[nf] = Bpl[idx];
            }
            #pragma unroll
            for (int mm = 0; mm < 4; ++mm) {
                #pragma unroll
                for (int nf = 0; nf < 4; ++nf) {
                    f32x4v t = acc[mm][nh * 4 + nf];
                    t = __builtin_amdgcn_mfma_f32_16x16x32_f16(ah[mm], bh[nf], t, 0, 0, 0);
                    t = __builtin_amdgcn_mfma_f32_16x16x32_f16(ah[mm], bl[nf], t, 0, 0, 0);
                    t = __builtin_amdgcn_mfma_f32_16x16x32_f16(al[mm], bh[nf], t, 0, 0, 0);
                    acc[mm][nh * 4 + nf] = t;
                }
            }
        }
    }

    // ---- epilogue: bias add, C store, fused column stats
    float bv[8], s[8], q[8];
    #pragma unroll
    for (int n = 0; n < 8; ++n) {
        bv[n] = bias[n0 + wc * 128 + n * 16 + (l & 15)];
        s[n] = 0.f; q[n] = 0.f;
    }
    #pragma unroll
    for (int m = 0; m < 4; ++m) {
        int row = m0 + wr * 64 + m * 16 + ((l >> 4) << 2);
        #pragma unroll
        for (int n = 0; n < 8; ++n) {
            int col = n0 + wc * 128 + n * 16 + (l & 15);
            float* cp = Cout + (size_t)row * N + col;
            #pragma unroll
            for (int j = 0; j < 4; ++j) {
                float v = acc[m][n][j] + bv[n];
                cp[(size_t)j * N] = v;
                s[n] += v; q[n] += v * v;
            }
        }
    }
    #pragma unroll
    for (int n = 0; n < 8; ++n) {
        s[n] += __shfl_xor(s[n], 16); s[n] += __shfl_xor(s[n], 32);
        q[n] += __shfl_xor(q[n], 16); q[n] += __shfl_xor(q[n], 32);
    }
    __syncthreads();
    if (wr == 1 && l < 16) {
        #pragma unroll
        for (int n = 0; n < 8; ++n) sred[(wc * 8 + n) * 16 + l] = make_float2(s[n], q[n]);
    }
    __syncthreads();
    if (wr == 0 && l < 16) {
        #pragma unroll
        for (int n = 0; n < 8; ++n) {
            float2 o = sred[(wc * 8 + n) * 16 + l];
            int col = n0 + wc * 128 + n * 16 + l;
            statp[(size_t)mb * N + col] = make_float2(s[n] + o.x, q[n] + o.y);
        }
    }
}

// ---------------------------------------------------------------------------
// Column-stat reduce: mean/var -> (scale, shift)
// ---------------------------------------------------------------------------
__global__ void reduce_stats_g(const float2* __restrict__ part, int nparts, int ncols,
                               const float* __restrict__ g, const float* __restrict__ be,
                               float2* __restrict__ scsh)
{
    int c = blockIdx.x * blockDim.x + threadIdx.x;
    if (c >= ncols) return;
    float s = 0.f, q = 0.f;
    for (int p = 0; p < nparts; ++p) {
        float2 v = part[(size_t)p * ncols + c];
        s += v.x; q += v.y;
    }
    const float invB = 1.f / 65536.f;
    float mu = s * invB, var = q * invB - mu * mu;
    float sc = g[c] * rsqrtf(var + 1e-5f);
    scsh[c] = make_float2(sc, be[c] - mu * sc);
}

// ---------------------------------------------------------------------------
// Head: y = relu(bn(h2)) @ W3 + b3, then per-row SO(3) projection (Jacobi).
// ---------------------------------------------------------------------------
__device__ __forceinline__ void jrot(float A[3][3], float V[3][3], int p, int q)
{
    float apq = A[p][q];
    float tau = A[q][q] - A[p][p];
    float a2  = 2.f * apq;
    float Dd  = fabsf(tau) + sqrtf(tau * tau + a2 * a2) + 1e-38f;
    float tt  = copysignf(1.f, tau) * a2 / Dd;
    float c   = 1.f / sqrtf(1.f + tt * tt);
    float s   = tt * c;
    int   r   = 3 - p - q;
    float App = A[p][p], Aqq = A[q][q];
    A[p][p] = App - tt * apq;
    A[q][q] = Aqq + tt * apq;
    A[p][q] = 0.f; A[q][p] = 0.f;
    float Arp = A[r][p], Arq = A[r][q];
    A[r][p] = c * Arp - s * Arq; A[p][r] = A[r][p];
    A[r][q] = s * Arp + c * Arq; A[q][r] = A[r][q];
    #pragma unroll
    for (int i = 0; i < 3; ++i) {
        float vp = V[i][p], vq = V[i][q];
        V[i][p] = c * vp - s * vq;
        V[i][q] = s * vp + c * vq;
    }
}

__global__ __launch_bounds__(256)
void head_svd(const float* __restrict__ H2, const float2* __restrict__ scsh2,
              const float* __restrict__ W3, const float* __restrict__ b3,
              float* __restrict__ out)
{
    __shared__ alignas(16) float  w3s[H2N * 12];
    __shared__ alignas(16) float2 ss[H2N];
    __shared__ float b3s[12];
    __shared__ alignas(16) float tile[64][257];

    const int t = threadIdx.x;
    for (int i = t; i < H2N * 12; i += 256) w3s[i] = W3[i];
    ss[t] = scsh2[t];
    if (t < 12) b3s[t] = b3[t];
    __syncthreads();

    const size_t rbase = (size_t)blockIdx.x * 256;
    const size_t row = rbase + t;
    float y[12];
    #pragma unroll
    for (int o = 0; o < 12; ++o) y[o] = b3s[o];

    for (int kc = 0; kc < 4; ++kc) {
        #pragma unroll
        for (int i = 0; i < 16; ++i) {
            int rr = (t >> 4) + i * 16;
            int k4 = (t & 15) * 4;
            float4 v = *(const float4*)(H2 + (rbase + rr) * H2N + kc * 64 + k4);
            float2 sA = ss[kc*64 + k4 + 0];
            float2 sB = ss[kc*64 + k4 + 1];
            float2 sC = ss[kc*64 + k4 + 2];
            float2 sD = ss[kc*64 + k4 + 3];
            tile[k4+0][rr] = fmaxf(fmaf(v.x, sA.x, sA.y), 0.f);
            tile[k4+1][rr] = fmaxf(fmaf(v.y, sB.x, sB.y), 0.f);
            tile[k4+2][rr] = fmaxf(fmaf(v.z, sC.x, sC.y), 0.f);
            tile[k4+3][rr] = fmaxf(fmaf(v.w, sD.x, sD.y), 0.f);
        }
        __syncthreads();
        #pragma unroll 4
        for (int k = 0; k < 64; ++k) {
            float v = tile[k][t];
            const float* wp = &w3s[(kc * 64 + k) * 12];
            #pragma unroll
            for (int o = 0; o < 12; ++o) y[o] = fmaf(v, wp[o], y[o]);
        }
        __syncthreads();
    }

    float mm[3][3];
    #pragma unroll
    for (int i = 0; i < 3; ++i)
        #pragma unroll
        for (int j = 0; j < 3; ++j) mm[i][j] = y[i * 3 + j];

    float Am[3][3];
    #pragma unroll
    for (int i = 0; i < 3; ++i)
        #pragma unroll
        for (int j = 0; j < 3; ++j)
            Am[i][j] = mm[0][i]*mm[0][j] + mm[1][i]*mm[1][j] + mm[2][i]*mm[2][j];

    float V[3][3] = {{1,0,0},{0,1,0},{0,0,1}};
    #pragma unroll
    for (int sweep = 0; sweep < 5; ++sweep) {
        jrot(Am, V, 0, 1);
        jrot(Am, V, 0, 2);
        jrot(Am, V, 1, 2);
    }
    float lam0 = Am[0][0], lam1 = Am[1][1], lam2 = Am[2][2];
    if (lam0 < lam1) { float tl=lam0; lam0=lam1; lam1=tl;
        #pragma unroll
        for (int i=0;i<3;++i){float tv=V[i][0];V[i][0]=V[i][1];V[i][1]=tv;} }
    if (lam0 < lam2) { float tl=lam0; lam0=lam2; lam2=tl;
        #pragma unroll
        for (int i=0;i<3;++i){float tv=V[i][0];V[i][0]=V[i][2];V[i][2]=tv;} }
    if (lam1 < lam2) { float tl=lam1; lam1=lam2; lam2=tl;
        #pragma unroll
        for (int i=0;i<3;++i){float tv=V[i][1];V[i][1]=V[i][2];V[i][2]=tv;} }

    float det =
          V[0][0]*(V[1][1]*V[2][2]-V[1][2]*V[2][1])
        - V[0][1]*(V[1][0]*V[2][2]-V[1][2]*V[2][0])
        + V[0][2]*(V[1][0]*V[2][1]-V[1][1]*V[2][0]);
    if (det < 0.f) { V[0][2] = -V[0][2]; V[1][2] = -V[1][2]; V[2][2] = -V[2][2]; }

    float u0[3], u1[3], u2[3];
    #pragma unroll
    for (int i = 0; i < 3; ++i)
        u0[i] = mm[i][0]*V[0][0] + mm[i][1]*V[1][0] + mm[i][2]*V[2][0];
    float nn0 = 1.f / sqrtf(u0[0]*u0[0] + u0[1]*u0[1] + u0[2]*u0[2] + 1e-30f);
    u0[0]*=nn0; u0[1]*=nn0; u0[2]*=nn0;
    #pragma unroll
    for (int i = 0; i < 3; ++i)
        u1[i] = mm[i][0]*V[0][1] + mm[i][1]*V[1][1] + mm[i][2]*V[2][1];
    float d01 = u0[0]*u1[0] + u0[1]*u1[1] + u0[2]*u1[2];
    u1[0]-=d01*u0[0]; u1[1]-=d01*u0[1]; u1[2]-=d01*u0[2];
    float nn1 = 1.f / sqrtf(u1[0]*u1[0] + u1[1]*u1[1] + u1[2]*u1[2] + 1e-30f);
    u1[0]*=nn1; u1[1]*=nn1; u1[2]*=nn1;
    u2[0] = u0[1]*u1[2] - u0[2]*u1[1];
    u2[1] = u0[2]*u1[0] - u0[0]*u1[2];
    u2[2] = u0[0]*u1[1] - u0[1]*u1[0];

    float* op = out + row * 12;
    #pragma unroll
    for (int i = 0; i < 3; ++i) {
        #pragma unroll
        for (int j = 0; j < 3; ++j)
            op[i*4 + j] = u0[i]*V[j][0] + u1[i]*V[j][1] + u2[i]*V[j][2];
        op[i*4 + 3] = y[9 + i];
    }
}

// ---------------------------------------------------------------------------
extern "C" void kernel_launch(void* const* d_in, const int* in_sizes, int n_in,
                              void* d_out, int out_size, void* d_ws, size_t ws_size,
                              hipStream_t stream)
{
    (void)in_sizes; (void)n_in; (void)out_size; (void)ws_size;

    const float* x   = (const float*)d_in[0];
    const float* W1  = (const float*)d_in[1];
    const float* b1  = (const float*)d_in[2];
    const float* g1  = (const float*)d_in[3];
    const float* be1 = (const float*)d_in[4];
    const float* W2  = (const float*)d_in[5];
    const float* b2  = (const float*)d_in[6];
    const float* g2  = (const float*)d_in[7];
    const float* be2 = (const float*)d_in[8];
    const float* W3  = (const float*)d_in[9];
    const float* b3  = (const float*)d_in[10];
    float* out = (float*)d_out;

    char* ws = (char*)d_ws;
    size_t off = 0;
    auto take = [&](size_t bytes) -> void* {
        void* p = ws + off;
        off += (bytes + 255) & ~(size_t)255;
        return p;
    };
    half8* w1h = (half8*)take((size_t)H1N * D_IN * 2);
    half8* w1l = (half8*)take((size_t)H1N * D_IN * 2);
    half8* w2h = (half8*)take((size_t)H2N * H1N * 2);
    half8* w2l = (half8*)take((size_t)H2N * H1N * 2);
    float*  h1    = (float*) take((size_t)B_ROWS * H1N * 4);
    float*  h2    = (float*) take((size_t)B_ROWS * H2N * 4);
    float2* part1 = (float2*)take((size_t)512 * H1N * 8);
    float2* part2 = (float2*)take((size_t)512 * H2N * 8);
    float2* scsh1 = (float2*)take((size_t)H1N * 8);
    float2* scsh2 = (float2*)take((size_t)H2N * 8);

    splitw_pk<<<dim3((D_IN/64) * (H1N/64)), dim3(256), 0, stream>>>(W1, w1h, w1l, D_IN, H1N);
    splitw_pk<<<dim3((H1N/64) * (H2N/64)), dim3(256), 0, stream>>>(W2, w2h, w2l, H1N, H2N);

    gemm_direct<D_IN, 2, false><<<dim3(1024), dim3(256), 0, stream>>>(
        x, w1h, w1l, b1, nullptr, h1, part1);
    reduce_stats_g<<<dim3(2), dim3(256), 0, stream>>>(part1, 512, H1N, g1, be1, scsh1);

    gemm_direct<H1N, 1, true><<<dim3(512), dim3(256), 0, stream>>>(
        h1, w2h, w2l, b2, scsh1, h2, part2);
    reduce_stats_g<<<dim3(1), dim3(256), 0, stream>>>(part2, 512, H2N, g2, be2, scsh2);

    head_svd<<<dim3(B_ROWS / 256), dim3(256), 0, stream>>>(h2, scsh2, W3, b3, out);
}

// Round 8
// 610.016 us; speedup vs baseline: 1.0900x; 1.0900x over previous
//
#include <hip/hip_runtime.h>

#define B_ROWS 65536
#define D_IN   1024
#define H1N    512
#define H2N    256

typedef _Float16 half8  __attribute__((ext_vector_type(8)));
typedef __fp16   fp16x2 __attribute__((ext_vector_type(2)));
typedef float    f32x4v __attribute__((ext_vector_type(4)));

#define GLOAD_LDS16(gp, lp) \
    __builtin_amdgcn_global_load_lds((const __attribute__((address_space(1))) void*)(gp), \
                                     (__attribute__((address_space(3))) void*)(lp), 16, 0, 0)

// ---------------------------------------------------------------------------
// Tiled transpose+split: W [Kd][Nd] fp32 -> wh/wl [Nd][Kd] fp16 hi/lo.
// ---------------------------------------------------------------------------
__global__ __launch_bounds__(256)
void splitw_t(const float* __restrict__ W, _Float16* __restrict__ wh,
              _Float16* __restrict__ wl, int Kd, int Nd)
{
    __shared__ float tile[64][65];
    const int t = threadIdx.x;
    const int ntn = Nd >> 6;
    const int k0 = (blockIdx.x / ntn) << 6;
    const int n0 = (blockIdx.x % ntn) << 6;

    {
        int r = t >> 4, c4 = (t & 15) << 2;
        #pragma unroll
        for (int i = 0; i < 4; ++i) {
            float4 v = *(const float4*)(W + (size_t)(k0 + r + i * 16) * Nd + n0 + c4);
            tile[r + i*16][c4+0] = v.x; tile[r + i*16][c4+1] = v.y;
            tile[r + i*16][c4+2] = v.z; tile[r + i*16][c4+3] = v.w;
        }
    }
    __syncthreads();
    {
        int n = t >> 2, kc = (t & 3) << 4;
        union { fp16x2 h2[8]; half8 h8[2]; } H, L;
        #pragma unroll
        for (int i = 0; i < 8; ++i) {
            float v0 = tile[kc + 2*i][n], v1 = tile[kc + 2*i + 1][n];
            float h0 = __int_as_float(__float_as_int(v0) & 0xFFFFE000);
            float h1 = __int_as_float(__float_as_int(v1) & 0xFFFFE000);
            H.h2[i] = __builtin_amdgcn_cvt_pkrtz(h0, h1);
            L.h2[i] = __builtin_amdgcn_cvt_pkrtz(v0 - h0, v1 - h1);
        }
        _Float16* ph = wh + (size_t)(n0 + n) * Kd + k0 + kc;
        _Float16* pl = wl + (size_t)(n0 + n) * Kd + k0 + kc;
        *(half8*)ph = H.h8[0]; *(half8*)(ph + 8) = H.h8[1];
        *(half8*)pl = L.h8[0]; *(half8*)(pl + 8) = L.h8[1];
    }
}

// ---------------------------------------------------------------------------
// Split-fp16 GEMM: C = [bnrelu?](A) @ Bt^T + bias, fused column stats.
// 128x128 tile, BK=32, 4 waves (2x2), wave tile 64x64, mfma 16x16x32 f16,
// 3 products (hh, hl, lh). A reg-staged (issue-early/write-late) with
// stage-time split (+BN+ReLU); B hi/lo via global_load_lds, swizzled source.
// 64 KB LDS -> 2 blocks/CU: independent blocks overlap barrier-drain vs MFMA.
// ---------------------------------------------------------------------------
template<int K, int NBn, bool BNRELU>   // NBn = N/128
__global__ __launch_bounds__(256, 2)
void gemm_fused(const float* __restrict__ Ain, const _Float16* __restrict__ Bth,
                const _Float16* __restrict__ Btl, const float* __restrict__ bias,
                const float2* __restrict__ scsh, float* __restrict__ Cout,
                float2* __restrict__ statp)
{
    constexpr int N  = NBn * 128;
    constexpr int NS = K / 32;
    __shared__ alignas(16) char smb[65536 + (BNRELU ? 4096 : 256)];
    // 8 planes x 8KB: AH0 AH1 AL0 AL1 BH0 BH1 BL0 BL1
    float2* scl = (float2*)(smb + 65536);

    const int tid = threadIdx.x;
    const int l = tid & 63;
    const int w = tid >> 6;
    const int wr = w >> 1, wc = w & 1;

    constexpr int NWG = (B_ROWS / 128) * NBn;
    const int bid = blockIdx.x;
    const int L  = (bid & 7) * (NWG >> 3) + (bid >> 3);   // bijective XCD swizzle
    const int mb = L / NBn, nb = L % NBn;
    const int m0 = mb << 7, n0 = nb << 7;

    const int ar = tid >> 1, ch = tid & 1;

    auto AH = [&](int buf) { return buf * 8192; };
    auto AL = [&](int buf) { return 16384 + buf * 8192; };
    auto BH = [&](int buf) { return 32768 + buf * 8192; };
    auto BL = [&](int buf) { return 49152 + buf * 8192; };

    float4 rga[4];
    auto load_regs = [&](int ks) {
        const float4* p = (const float4*)(Ain + (size_t)(m0 + ar) * K + ks * 32 + ch * 16);
        rga[0] = p[0]; rga[1] = p[1]; rga[2] = p[2]; rga[3] = p[3];
    };

    auto stageB = [&](int buf, int ks) {
        #pragma unroll
        for (int i = 0; i < 2; ++i) {
            int rbase = (w * 2 + i) * 16;
            int r = rbase + (l >> 2);
            int c = (l & 3) ^ ((r >> 1) & 3);
            const _Float16* gh = Bth + (size_t)(n0 + r) * K + ks * 32 + c * 8;
            const _Float16* gl = Btl + (size_t)(n0 + r) * K + ks * 32 + c * 8;
            GLOAD_LDS16(gh, smb + BH(buf) + rbase * 64);
            GLOAD_LDS16(gl, smb + BL(buf) + rbase * 64);
        }
    };

    auto proc_write = [&](int buf, int ks) {
        float v[16];
        #pragma unroll
        for (int p = 0; p < 4; ++p) {
            v[p*4+0] = rga[p].x; v[p*4+1] = rga[p].y;
            v[p*4+2] = rga[p].z; v[p*4+3] = rga[p].w;
        }
        if constexpr (BNRELU) {
            const float2* sp = scl + ks * 32 + ch * 16;   // global k indexing
            #pragma unroll
            for (int i = 0; i < 16; ++i) {
                float2 s2 = sp[i];
                v[i] = fmaxf(fmaf(v[i], s2.x, s2.y), 0.f);
            }
        }
        union { fp16x2 h2[4]; half8 h8; } H[2], Lo[2];
        #pragma unroll
        for (int hb = 0; hb < 2; ++hb) {
            #pragma unroll
            for (int i = 0; i < 4; ++i) {
                float a0 = v[hb*8 + 2*i], a1 = v[hb*8 + 2*i + 1];
                float h0 = __int_as_float(__float_as_int(a0) & 0xFFFFE000);
                float h1 = __int_as_float(__float_as_int(a1) & 0xFFFFE000);
                H[hb].h2[i]  = __builtin_amdgcn_cvt_pkrtz(h0, h1);
                Lo[hb].h2[i] = __builtin_amdgcn_cvt_pkrtz(a0 - h0, a1 - h1);
            }
        }
        char* ph = smb + AH(buf) + ar * 64;
        char* pl = smb + AL(buf) + ar * 64;
        int sw = (ar >> 1) & 3;
        *(half8*)(ph + (((ch*2)     ^ sw) * 16)) = H[0].h8;
        *(half8*)(ph + (((ch*2 + 1) ^ sw) * 16)) = H[1].h8;
        *(half8*)(pl + (((ch*2)     ^ sw) * 16)) = Lo[0].h8;
        *(half8*)(pl + (((ch*2 + 1) ^ sw) * 16)) = Lo[1].h8;
    };

    // ---- prologue
    if constexpr (BNRELU) {
        for (int i = tid; i < K; i += 256) scl[i] = scsh[i];
    }
    (void)scsh;
    load_regs(0);
    stageB(0, 0);
    __syncthreads();                 // scl ready + B(0) staged
    proc_write(0, 0);
    __syncthreads();                 // A(0) planes ready

    f32x4v acc[4][4] = {};
    for (int ks = 0; ks < NS; ++ks) {
        const int buf = ks & 1;
        if (ks < NS - 1) { load_regs(ks + 1); stageB(buf ^ 1, ks + 1); }

        half8 bh[4], bl[4], ah[4], al[4];
        #pragma unroll
        for (int n = 0; n < 4; ++n) {
            int r = wc * 64 + n * 16 + (l & 15);
            int c = (l >> 4) ^ ((r >> 1) & 3);
            bh[n] = *(const half8*)(smb + BH(buf) + r * 64 + c * 16);
            bl[n] = *(const half8*)(smb + BL(buf) + r * 64 + c * 16);
        }
        #pragma unroll
        for (int m = 0; m < 4; ++m) {
            int r = wr * 64 + m * 16 + (l & 15);
            int c = (l >> 4) ^ ((r >> 1) & 3);
            ah[m] = *(const half8*)(smb + AH(buf) + r * 64 + c * 16);
            al[m] = *(const half8*)(smb + AL(buf) + r * 64 + c * 16);
        }
        #pragma unroll
        for (int m = 0; m < 4; ++m) {
            #pragma unroll
            for (int n = 0; n < 4; ++n) {
                f32x4v t = acc[m][n];
                t = __builtin_amdgcn_mfma_f32_16x16x32_f16(ah[m], bh[n], t, 0, 0, 0);
                t = __builtin_amdgcn_mfma_f32_16x16x32_f16(ah[m], bl[n], t, 0, 0, 0);
                t = __builtin_amdgcn_mfma_f32_16x16x32_f16(al[m], bh[n], t, 0, 0, 0);
                acc[m][n] = t;
            }
        }
        if (ks < NS - 1) proc_write(buf ^ 1, ks + 1);
        __syncthreads();
    }

    // ---- epilogue: bias add, C store, fused column stats
    float bv[4], s[4], q[4];
    #pragma unroll
    for (int n = 0; n < 4; ++n) {
        bv[n] = bias[n0 + wc * 64 + n * 16 + (l & 15)];
        s[n] = 0.f; q[n] = 0.f;
    }
    #pragma unroll
    for (int m = 0; m < 4; ++m) {
        int row = m0 + wr * 64 + m * 16 + ((l >> 4) << 2);
        #pragma unroll
        for (int n = 0; n < 4; ++n) {
            int col = n0 + wc * 64 + n * 16 + (l & 15);
            float* cp = Cout + (size_t)row * N + col;
            #pragma unroll
            for (int j = 0; j < 4; ++j) {
                float v = acc[m][n][j] + bv[n];
                cp[(size_t)j * N] = v;
                s[n] += v; q[n] += v * v;
            }
        }
    }
    #pragma unroll
    for (int n = 0; n < 4; ++n) {
        s[n] += __shfl_xor(s[n], 16); s[n] += __shfl_xor(s[n], 32);
        q[n] += __shfl_xor(q[n], 16); q[n] += __shfl_xor(q[n], 32);
    }
    __syncthreads();
    float2* red = (float2*)smb;
    if (wr == 1 && l < 16) {
        #pragma unroll
        for (int n = 0; n < 4; ++n) red[(wc * 4 + n) * 16 + l] = make_float2(s[n], q[n]);
    }
    __syncthreads();
    if (wr == 0 && l < 16) {
        #pragma unroll
        for (int n = 0; n < 4; ++n) {
            float2 o = red[(wc * 4 + n) * 16 + l];
            int col = n0 + wc * 64 + n * 16 + l;
            statp[(size_t)mb * N + col] = make_float2(s[n] + o.x, q[n] + o.y);
        }
    }
}

// ---------------------------------------------------------------------------
// Column-stat reduce: mean/var -> (scale, shift)
// ---------------------------------------------------------------------------
__global__ void reduce_stats_g(const float2* __restrict__ part, int nparts, int ncols,
                               const float* __restrict__ g, const float* __restrict__ be,
                               float2* __restrict__ scsh)
{
    int c = blockIdx.x * blockDim.x + threadIdx.x;
    if (c >= ncols) return;
    float s = 0.f, q = 0.f;
    for (int p = 0; p < nparts; ++p) {
        float2 v = part[(size_t)p * ncols + c];
        s += v.x; q += v.y;
    }
    const float invB = 1.f / 65536.f;
    float mu = s * invB, var = q * invB - mu * mu;
    float sc = g[c] * rsqrtf(var + 1e-5f);
    scsh[c] = make_float2(sc, be[c] - mu * sc);
}

// ---------------------------------------------------------------------------
// Head: y = relu(bn(h2)) @ W3 + b3, then per-row SO(3) projection (Jacobi).
// ---------------------------------------------------------------------------
__device__ __forceinline__ void jrot(float A[3][3], float V[3][3], int p, int q)
{
    float apq = A[p][q];
    float tau = A[q][q] - A[p][p];
    float a2  = 2.f * apq;
    float Dd  = fabsf(tau) + sqrtf(tau * tau + a2 * a2) + 1e-38f;
    float tt  = copysignf(1.f, tau) * a2 / Dd;
    float c   = 1.f / sqrtf(1.f + tt * tt);
    float s   = tt * c;
    int   r   = 3 - p - q;
    float App = A[p][p], Aqq = A[q][q];
    A[p][p] = App - tt * apq;
    A[q][q] = Aqq + tt * apq;
    A[p][q] = 0.f; A[q][p] = 0.f;
    float Arp = A[r][p], Arq = A[r][q];
    A[r][p] = c * Arp - s * Arq; A[p][r] = A[r][p];
    A[r][q] = s * Arp + c * Arq; A[q][r] = A[r][q];
    #pragma unroll
    for (int i = 0; i < 3; ++i) {
        float vp = V[i][p], vq = V[i][q];
        V[i][p] = c * vp - s * vq;
        V[i][q] = s * vp + c * vq;
    }
}

__global__ __launch_bounds__(256)
void head_svd(const float* __restrict__ H2, const float2* __restrict__ scsh2,
              const float* __restrict__ W3, const float* __restrict__ b3,
              float* __restrict__ out)
{
    __shared__ alignas(16) float  w3s[H2N * 12];
    __shared__ alignas(16) float2 ss[H2N];
    __shared__ float b3s[12];
    __shared__ alignas(16) float tile[64][257];

    const int t = threadIdx.x;
    for (int i = t; i < H2N * 12; i += 256) w3s[i] = W3[i];
    ss[t] = scsh2[t];
    if (t < 12) b3s[t] = b3[t];
    __syncthreads();

    const size_t rbase = (size_t)blockIdx.x * 256;
    const size_t row = rbase + t;
    float y[12];
    #pragma unroll
    for (int o = 0; o < 12; ++o) y[o] = b3s[o];

    for (int kc = 0; kc < 4; ++kc) {
        #pragma unroll
        for (int i = 0; i < 16; ++i) {
            int rr = (t >> 4) + i * 16;
            int k4 = (t & 15) * 4;
            float4 v = *(const float4*)(H2 + (rbase + rr) * H2N + kc * 64 + k4);
            float2 sA = ss[kc*64 + k4 + 0];
            float2 sB = ss[kc*64 + k4 + 1];
            float2 sC = ss[kc*64 + k4 + 2];
            float2 sD = ss[kc*64 + k4 + 3];
            tile[k4+0][rr] = fmaxf(fmaf(v.x, sA.x, sA.y), 0.f);
            tile[k4+1][rr] = fmaxf(fmaf(v.y, sB.x, sB.y), 0.f);
            tile[k4+2][rr] = fmaxf(fmaf(v.z, sC.x, sC.y), 0.f);
            tile[k4+3][rr] = fmaxf(fmaf(v.w, sD.x, sD.y), 0.f);
        }
        __syncthreads();
        #pragma unroll 4
        for (int k = 0; k < 64; ++k) {
            float v = tile[k][t];
            const float* wp = &w3s[(kc * 64 + k) * 12];
            #pragma unroll
            for (int o = 0; o < 12; ++o) y[o] = fmaf(v, wp[o], y[o]);
        }
        __syncthreads();
    }

    float mm[3][3];
    #pragma unroll
    for (int i = 0; i < 3; ++i)
        #pragma unroll
        for (int j = 0; j < 3; ++j) mm[i][j] = y[i * 3 + j];

    float Am[3][3];
    #pragma unroll
    for (int i = 0; i < 3; ++i)
        #pragma unroll
        for (int j = 0; j < 3; ++j)
            Am[i][j] = mm[0][i]*mm[0][j] + mm[1][i]*mm[1][j] + mm[2][i]*mm[2][j];

    float V[3][3] = {{1,0,0},{0,1,0},{0,0,1}};
    #pragma unroll
    for (int sweep = 0; sweep < 5; ++sweep) {
        jrot(Am, V, 0, 1);
        jrot(Am, V, 0, 2);
        jrot(Am, V, 1, 2);
    }
    float lam0 = Am[0][0], lam1 = Am[1][1], lam2 = Am[2][2];
    if (lam0 < lam1) { float tl=lam0; lam0=lam1; lam1=tl;
        #pragma unroll
        for (int i=0;i<3;++i){float tv=V[i][0];V[i][0]=V[i][1];V[i][1]=tv;} }
    if (lam0 < lam2) { float tl=lam0; lam0=lam2; lam2=tl;
        #pragma unroll
        for (int i=0;i<3;++i){float tv=V[i][0];V[i][0]=V[i][2];V[i][2]=tv;} }
    if (lam1 < lam2) { float tl=lam1; lam1=lam2; lam2=tl;
        #pragma unroll
        for (int i=0;i<3;++i){float tv=V[i][1];V[i][1]=V[i][2];V[i][2]=tv;} }

    float det =
          V[0][0]*(V[1][1]*V[2][2]-V[1][2]*V[2][1])
        - V[0][1]*(V[1][0]*V[2][2]-V[1][2]*V[2][0])
        + V[0][2]*(V[1][0]*V[2][1]-V[1][1]*V[2][0]);
    if (det < 0.f) { V[0][2] = -V[0][2]; V[1][2] = -V[1][2]; V[2][2] = -V[2][2]; }

    float u0[3], u1[3], u2[3];
    #pragma unroll
    for (int i = 0; i < 3; ++i)
        u0[i] = mm[i][0]*V[0][0] + mm[i][1]*V[1][0] + mm[i][2]*V[2][0];
    float nn0 = 1.f / sqrtf(u0[0]*u0[0] + u0[1]*u0[1] + u0[2]*u0[2] + 1e-30f);
    u0[0]*=nn0; u0[1]*=nn0; u0[2]*=nn0;
    #pragma unroll
    for (int i = 0; i < 3; ++i)
        u1[i] = mm[i][0]*V[0][1] + mm[i][1]*V[1][1] + mm[i][2]*V[2][1];
    float d01 = u0[0]*u1[0] + u0[1]*u1[1] + u0[2]*u1[2];
    u1[0]-=d01*u0[0]; u1[1]-=d01*u0[1]; u1[2]-=d01*u0[2];
    float nn1 = 1.f / sqrtf(u1[0]*u1[0] + u1[1]*u1[1] + u1[2]*u1[2] + 1e-30f);
    u1[0]*=nn1; u1[1]*=nn1; u1[2]*=nn1;
    u2[0] = u0[1]*u1[2] - u0[2]*u1[1];
    u2[1] = u0[2]*u1[0] - u0[0]*u1[2];
    u2[2] = u0[0]*u1[1] - u0[1]*u1[0];

    float* op = out + row * 12;
    #pragma unroll
    for (int i = 0; i < 3; ++i) {
        #pragma unroll
        for (int j = 0; j < 3; ++j)
            op[i*4 + j] = u0[i]*V[j][0] + u1[i]*V[j][1] + u2[i]*V[j][2];
        op[i*4 + 3] = y[9 + i];
    }
}

// ---------------------------------------------------------------------------
extern "C" void kernel_launch(void* const* d_in, const int* in_sizes, int n_in,
                              void* d_out, int out_size, void* d_ws, size_t ws_size,
                              hipStream_t stream)
{
    (void)in_sizes; (void)n_in; (void)out_size; (void)ws_size;

    const float* x   = (const float*)d_in[0];
    const float* W1  = (const float*)d_in[1];
    const float* b1  = (const float*)d_in[2];
    const float* g1  = (const float*)d_in[3];
    const float* be1 = (const float*)d_in[4];
    const float* W2  = (const float*)d_in[5];
    const float* b2  = (const float*)d_in[6];
    const float* g2  = (const float*)d_in[7];
    const float* be2 = (const float*)d_in[8];
    const float* W3  = (const float*)d_in[9];
    const float* b3  = (const float*)d_in[10];
    float* out = (float*)d_out;

    char* ws = (char*)d_ws;
    size_t off = 0;
    auto take = [&](size_t bytes) -> void* {
        void* p = ws + off;
        off += (bytes + 255) & ~(size_t)255;
        return p;
    };
    _Float16* w1h = (_Float16*)take((size_t)H1N * D_IN * 2);
    _Float16* w1l = (_Float16*)take((size_t)H1N * D_IN * 2);
    _Float16* w2h = (_Float16*)take((size_t)H2N * H1N * 2);
    _Float16* w2l = (_Float16*)take((size_t)H2N * H1N * 2);
    float*  h1    = (float*) take((size_t)B_ROWS * H1N * 4);
    float*  h2    = (float*) take((size_t)B_ROWS * H2N * 4);
    float2* part1 = (float2*)take((size_t)512 * H1N * 8);
    float2* part2 = (float2*)take((size_t)512 * H2N * 8);
    float2* scsh1 = (float2*)take((size_t)H1N * 8);
    float2* scsh2 = (float2*)take((size_t)H2N * 8);

    splitw_t<<<dim3((D_IN/64) * (H1N/64)), dim3(256), 0, stream>>>(W1, w1h, w1l, D_IN, H1N);
    splitw_t<<<dim3((H1N/64) * (H2N/64)), dim3(256), 0, stream>>>(W2, w2h, w2l, H1N, H2N);

    gemm_fused<D_IN, 4, false><<<dim3(2048), dim3(256), 0, stream>>>(
        x, w1h, w1l, b1, nullptr, h1, part1);
    reduce_stats_g<<<dim3(2), dim3(256), 0, stream>>>(part1, 512, H1N, g1, be1, scsh1);

    gemm_fused<H1N, 2, true><<<dim3(1024), dim3(256), 0, stream>>>(
        h1, w2h, w2l, b2, scsh1, h2, part2);
    reduce_stats_g<<<dim3(1), dim3(256), 0, stream>>>(part2, 512, H2N, g2, be2, scsh2);

    head_svd<<<dim3(B_ROWS / 256), dim3(256), 0, stream>>>(h2, scsh2, W3, b3, out);
}

// Round 9
// 446.201 us; speedup vs baseline: 1.4901x; 1.3671x over previous
//
#include <hip/hip_runtime.h>

#define B_ROWS 65536
#define D_IN   1024
#define H1N    512
#define H2N    256

typedef _Float16 half8  __attribute__((ext_vector_type(8)));
typedef __fp16   fp16x2 __attribute__((ext_vector_type(2)));
typedef float    f32x4v __attribute__((ext_vector_type(4)));

#define GLOAD_LDS16(gp, lp) \
    __builtin_amdgcn_global_load_lds((const __attribute__((address_space(1))) void*)(gp), \
                                     (__attribute__((address_space(3))) void*)(lp), 16, 0, 0)

// ---------------------------------------------------------------------------
// Tiled transpose+split: W [Kd][Nd] fp32 -> wh/wl [Nd][Kd] fp16 hi/lo.
// ---------------------------------------------------------------------------
__global__ __launch_bounds__(256)
void splitw_t(const float* __restrict__ W, _Float16* __restrict__ wh,
              _Float16* __restrict__ wl, int Kd, int Nd)
{
    __shared__ float tile[64][65];
    const int t = threadIdx.x;
    const int ntn = Nd >> 6;
    const int k0 = (blockIdx.x / ntn) << 6;
    const int n0 = (blockIdx.x % ntn) << 6;

    {
        int r = t >> 4, c4 = (t & 15) << 2;
        #pragma unroll
        for (int i = 0; i < 4; ++i) {
            float4 v = *(const float4*)(W + (size_t)(k0 + r + i * 16) * Nd + n0 + c4);
            tile[r + i*16][c4+0] = v.x; tile[r + i*16][c4+1] = v.y;
            tile[r + i*16][c4+2] = v.z; tile[r + i*16][c4+3] = v.w;
        }
    }
    __syncthreads();
    {
        int n = t >> 2, kc = (t & 3) << 4;
        union { fp16x2 h2[8]; half8 h8[2]; } H, L;
        #pragma unroll
        for (int i = 0; i < 8; ++i) {
            float v0 = tile[kc + 2*i][n], v1 = tile[kc + 2*i + 1][n];
            float h0 = __int_as_float(__float_as_int(v0) & 0xFFFFE000);
            float h1 = __int_as_float(__float_as_int(v1) & 0xFFFFE000);
            H.h2[i] = __builtin_amdgcn_cvt_pkrtz(h0, h1);
            L.h2[i] = __builtin_amdgcn_cvt_pkrtz(v0 - h0, v1 - h1);
        }
        _Float16* ph = wh + (size_t)(n0 + n) * Kd + k0 + kc;
        _Float16* pl = wl + (size_t)(n0 + n) * Kd + k0 + kc;
        *(half8*)ph = H.h8[0]; *(half8*)(ph + 8) = H.h8[1];
        *(half8*)pl = L.h8[0]; *(half8*)(pl + 8) = L.h8[1];
    }
}

// ---------------------------------------------------------------------------
// Split-fp16 GEMM with COUNTED-vmcnt double-buffer pipeline (T3+T4):
// 256x256 tile, BK=32, 8 waves (2x4), wave tile 128x64, mfma 16x16x32 f16,
// 3 products (hh, hl, lh). A fp32 + B hi/lo staged via global_load_lds
// (8 loads/wave/stage). Per K-step:
//   stage(j+1) ; s_waitcnt vmcnt(8)  <- stage(j) landed, stage(j+1) in flight
//   s_barrier  ; ds_read buf(j) + MFMA (setprio)
//   s_barrier  <- all reads of buf(j) retired -> next iter may overwrite it
// Race audit: writes to buf c^1 issue only after prev post-MFMA barrier.
// ---------------------------------------------------------------------------
template<int K, int NB, bool BNRELU>
__global__ __launch_bounds__(512, 1)
void gemm_fused(const float* __restrict__ Ain, const _Float16* __restrict__ Bth,
                const _Float16* __restrict__ Btl, const float* __restrict__ bias,
                const float2* __restrict__ scsh, float* __restrict__ Cout,
                float2* __restrict__ statp)
{
    constexpr int N  = NB * 256;
    constexpr int NS = K / 32;
    __shared__ alignas(16) char smb[131072 + 4096];
    const int A0 = 0,      A1  = 32768;                      // fp32 A: 256x128B
    const int BH0 = 65536, BH1 = 81920;                      // fp16 Bhi: 256x64B
    const int BL0 = 98304, BL1 = 114688;                     // fp16 Blo
    float2* scl = (float2*)(smb + 131072);

    const int tid = threadIdx.x;
    const int l = tid & 63;
    const int w = tid >> 6;
    const int wr = w >> 2, wc = w & 3;

    const int bid = blockIdx.x;
    constexpr int CPX = 32 * NB;
    const int L  = (bid & 7) * CPX + (bid >> 3);             // bijective XCD swizzle
    const int mb = L / NB, nb = L % NB;
    const int m0 = mb << 8, n0 = nb << 8;

    auto stageAll = [&](int ks, int offA, int offBH, int offBL) {
        #pragma unroll
        for (int i = 0; i < 4; ++i) {                        // A: 4 issues/wave
            int rbase = w * 32 + i * 8;
            int r = rbase + (l >> 3);
            int c = (l & 7) ^ (r & 7);
            const float* g = Ain + (size_t)(m0 + r) * K + ks * 32 + c * 4;
            GLOAD_LDS16(g, smb + offA + rbase * 128);
        }
        #pragma unroll
        for (int i = 0; i < 2; ++i) {                        // Bhi/Blo: 2+2
            int rbase = (w * 2 + i) * 16;
            int r = rbase + (l >> 2);
            int c = (l & 3) ^ ((r >> 1) & 3);
            const _Float16* gh = Bth + (size_t)(n0 + r) * K + ks * 32 + c * 8;
            const _Float16* gl = Btl + (size_t)(n0 + r) * K + ks * 32 + c * 8;
            GLOAD_LDS16(gh, smb + offBH + rbase * 64);
            GLOAD_LDS16(gl, smb + offBL + rbase * 64);
        }
    };

    half8 bh[4], bl[4], ah[4], al[4];
    float2 ssreg[8];
    f32x4v acc[8][4] = {};

    auto loadss = [&](int ks) {
        if constexpr (BNRELU) {
            // global columns for this lane: va -> 8*(l>>4)+0..3, vb -> +4..7
            const float2* sp = scl + ks * 32 + ((l >> 4) << 3);
            #pragma unroll
            for (int i = 0; i < 8; ++i) ssreg[i] = sp[i];
        }
        (void)ks;
    };

    auto dsreadB = [&](int offBH, int offBL) {
        #pragma unroll
        for (int n = 0; n < 4; ++n) {
            int r = wc * 64 + n * 16 + (l & 15);
            int c = (l >> 4) ^ ((r >> 1) & 3);
            bh[n] = *(const half8*)(smb + offBH + r * 64 + c * 16);
            bl[n] = *(const half8*)(smb + offBL + r * 64 + c * 16);
        }
    };

    auto dsreadA = [&](int offA, int mh) {
        #pragma unroll
        for (int mm = 0; mm < 4; ++mm) {
            int r = wr * 128 + (mh * 4 + mm) * 16 + (l & 15);
            const char* base = smb + offA + r * 128;
            int c0 = ((l >> 4) * 2) ^ (r & 7);
            int c1 = (((l >> 4) * 2) | 1) ^ (r & 7);
            f32x4v va = *(const f32x4v*)(base + c0 * 16);
            f32x4v vb = *(const f32x4v*)(base + c1 * 16);
            if constexpr (BNRELU) {
                #pragma unroll
                for (int e = 0; e < 4; ++e) {
                    va[e] = fmaxf(fmaf(va[e], ssreg[e].x,     ssreg[e].y),     0.f);
                    vb[e] = fmaxf(fmaf(vb[e], ssreg[4 + e].x, ssreg[4 + e].y), 0.f);
                }
            }
            union { fp16x2 h2[4]; half8 h8; } H, Lo;
            #pragma unroll
            for (int i = 0; i < 4; ++i) {
                float a0 = (i < 2) ? va[2*i]     : vb[2*(i-2)];
                float a1 = (i < 2) ? va[2*i + 1] : vb[2*(i-2) + 1];
                float h0 = __int_as_float(__float_as_int(a0) & 0xFFFFE000);
                float h1 = __int_as_float(__float_as_int(a1) & 0xFFFFE000);
                H.h2[i]  = __builtin_amdgcn_cvt_pkrtz(h0, h1);
                Lo.h2[i] = __builtin_amdgcn_cvt_pkrtz(a0 - h0, a1 - h1);
            }
            ah[mm] = H.h8; al[mm] = Lo.h8;
        }
    };

    auto mfma48 = [&](int mh) {
        __builtin_amdgcn_s_setprio(1);
        #pragma unroll
        for (int mm = 0; mm < 4; ++mm) {
            #pragma unroll
            for (int n = 0; n < 4; ++n) {
                f32x4v t = acc[mh * 4 + mm][n];
                t = __builtin_amdgcn_mfma_f32_16x16x32_f16(ah[mm], bh[n], t, 0, 0, 0);
                t = __builtin_amdgcn_mfma_f32_16x16x32_f16(ah[mm], bl[n], t, 0, 0, 0);
                t = __builtin_amdgcn_mfma_f32_16x16x32_f16(al[mm], bh[n], t, 0, 0, 0);
                acc[mh * 4 + mm][n] = t;
            }
        }
        __builtin_amdgcn_s_setprio(0);
    };

    // ---- prologue
    stageAll(0, A0, BH0, BL0);
    if constexpr (BNRELU) {
        for (int i = tid; i < K; i += 512) scl[i] = scsh[i];
        __syncthreads();          // scl visible (also drains stage(0); one-time)
    }
    (void)scsh;

    for (int ks = 0; ks < NS; ++ks) {
        const int buf = ks & 1;
        const int cA  = buf ? A1  : A0,  nA  = buf ? A0  : A1;
        const int cBH = buf ? BH1 : BH0, nBH = buf ? BH0 : BH1;
        const int cBL = buf ? BL1 : BL0, nBL = buf ? BL0 : BL1;

        if (ks < NS - 1) {
            stageAll(ks + 1, nA, nBH, nBL);                  // 8 loads in flight
            asm volatile("s_waitcnt vmcnt(8)" ::: "memory"); // stage(ks) landed
        } else {
            asm volatile("s_waitcnt vmcnt(0)" ::: "memory");
        }
        __builtin_amdgcn_s_barrier();                        // buf(ks) ready
        asm volatile("" ::: "memory");

        loadss(ks);
        dsreadB(cBH, cBL);
        dsreadA(cA, 0);
        mfma48(0);
        dsreadA(cA, 1);
        mfma48(1);

        asm volatile("" ::: "memory");
        __builtin_amdgcn_s_barrier();                        // reads of buf(ks) done
    }

    // ---- epilogue: bias add, C store, fused column stats
    float bv[4], s[4], q[4];
    #pragma unroll
    for (int n = 0; n < 4; ++n) {
        bv[n] = bias[n0 + wc * 64 + n * 16 + (l & 15)];
        s[n] = 0.f; q[n] = 0.f;
    }
    #pragma unroll
    for (int m = 0; m < 8; ++m) {
        int row = m0 + wr * 128 + m * 16 + ((l >> 4) << 2);
        #pragma unroll
        for (int n = 0; n < 4; ++n) {
            int col = n0 + wc * 64 + n * 16 + (l & 15);
            float* cp = Cout + (size_t)row * N + col;
            #pragma unroll
            for (int j = 0; j < 4; ++j) {
                float v = acc[m][n][j] + bv[n];
                cp[(size_t)j * N] = v;
                s[n] += v; q[n] += v * v;
            }
        }
    }
    #pragma unroll
    for (int n = 0; n < 4; ++n) {
        s[n] += __shfl_xor(s[n], 16); s[n] += __shfl_xor(s[n], 32);
        q[n] += __shfl_xor(q[n], 16); q[n] += __shfl_xor(q[n], 32);
    }
    __syncthreads();
    float2* red = (float2*)smb;
    if (wr == 1 && l < 16) {
        #pragma unroll
        for (int n = 0; n < 4; ++n) red[(wc * 4 + n) * 16 + l] = make_float2(s[n], q[n]);
    }
    __syncthreads();
    if (wr == 0 && l < 16) {
        #pragma unroll
        for (int n = 0; n < 4; ++n) {
            float2 o = red[(wc * 4 + n) * 16 + l];
            int col = n0 + wc * 64 + n * 16 + l;
            statp[(size_t)mb * N + col] = make_float2(s[n] + o.x, q[n] + o.y);
        }
    }
}

// ---------------------------------------------------------------------------
// Column-stat reduce: mean/var -> (scale, shift)
// ---------------------------------------------------------------------------
__global__ void reduce_stats_g(const float2* __restrict__ part, int nparts, int ncols,
                               const float* __restrict__ g, const float* __restrict__ be,
                               float2* __restrict__ scsh)
{
    int c = blockIdx.x * blockDim.x + threadIdx.x;
    if (c >= ncols) return;
    float s = 0.f, q = 0.f;
    for (int p = 0; p < nparts; ++p) {
        float2 v = part[(size_t)p * ncols + c];
        s += v.x; q += v.y;
    }
    const float invB = 1.f / 65536.f;
    float mu = s * invB, var = q * invB - mu * mu;
    float sc = g[c] * rsqrtf(var + 1e-5f);
    scsh[c] = make_float2(sc, be[c] - mu * sc);
}

// ---------------------------------------------------------------------------
// Head: y = relu(bn(h2)) @ W3 + b3, then per-row SO(3) projection (Jacobi).
// ---------------------------------------------------------------------------
__device__ __forceinline__ void jrot(float A[3][3], float V[3][3], int p, int q)
{
    float apq = A[p][q];
    float tau = A[q][q] - A[p][p];
    float a2  = 2.f * apq;
    float Dd  = fabsf(tau) + sqrtf(tau * tau + a2 * a2) + 1e-38f;
    float tt  = copysignf(1.f, tau) * a2 / Dd;
    float c   = 1.f / sqrtf(1.f + tt * tt);
    float s   = tt * c;
    int   r   = 3 - p - q;
    float App = A[p][p], Aqq = A[q][q];
    A[p][p] = App - tt * apq;
    A[q][q] = Aqq + tt * apq;
    A[p][q] = 0.f; A[q][p] = 0.f;
    float Arp = A[r][p], Arq = A[r][q];
    A[r][p] = c * Arp - s * Arq; A[p][r] = A[r][p];
    A[r][q] = s * Arp + c * Arq; A[q][r] = A[r][q];
    #pragma unroll
    for (int i = 0; i < 3; ++i) {
        float vp = V[i][p], vq = V[i][q];
        V[i][p] = c * vp - s * vq;
        V[i][q] = s * vp + c * vq;
    }
}

__global__ __launch_bounds__(256)
void head_svd(const float* __restrict__ H2, const float2* __restrict__ scsh2,
              const float* __restrict__ W3, const float* __restrict__ b3,
              float* __restrict__ out)
{
    __shared__ alignas(16) float  w3s[H2N * 12];
    __shared__ alignas(16) float2 ss[H2N];
    __shared__ float b3s[12];
    __shared__ alignas(16) float tile[64][257];

    const int t = threadIdx.x;
    for (int i = t; i < H2N * 12; i += 256) w3s[i] = W3[i];
    ss[t] = scsh2[t];
    if (t < 12) b3s[t] = b3[t];
    __syncthreads();

    const size_t rbase = (size_t)blockIdx.x * 256;
    const size_t row = rbase + t;
    float y[12];
    #pragma unroll
    for (int o = 0; o < 12; ++o) y[o] = b3s[o];

    for (int kc = 0; kc < 4; ++kc) {
        #pragma unroll
        for (int i = 0; i < 16; ++i) {
            int rr = (t >> 4) + i * 16;
            int k4 = (t & 15) * 4;
            float4 v = *(const float4*)(H2 + (rbase + rr) * H2N + kc * 64 + k4);
            float2 sA = ss[kc*64 + k4 + 0];
            float2 sB = ss[kc*64 + k4 + 1];
            float2 sC = ss[kc*64 + k4 + 2];
            float2 sD = ss[kc*64 + k4 + 3];
            tile[k4+0][rr] = fmaxf(fmaf(v.x, sA.x, sA.y), 0.f);
            tile[k4+1][rr] = fmaxf(fmaf(v.y, sB.x, sB.y), 0.f);
            tile[k4+2][rr] = fmaxf(fmaf(v.z, sC.x, sC.y), 0.f);
            tile[k4+3][rr] = fmaxf(fmaf(v.w, sD.x, sD.y), 0.f);
        }
        __syncthreads();
        #pragma unroll 4
        for (int k = 0; k < 64; ++k) {
            float v = tile[k][t];
            const float* wp = &w3s[(kc * 64 + k) * 12];
            #pragma unroll
            for (int o = 0; o < 12; ++o) y[o] = fmaf(v, wp[o], y[o]);
        }
        __syncthreads();
    }

    float mm[3][3];
    #pragma unroll
    for (int i = 0; i < 3; ++i)
        #pragma unroll
        for (int j = 0; j < 3; ++j) mm[i][j] = y[i * 3 + j];

    float Am[3][3];
    #pragma unroll
    for (int i = 0; i < 3; ++i)
        #pragma unroll
        for (int j = 0; j < 3; ++j)
            Am[i][j] = mm[0][i]*mm[0][j] + mm[1][i]*mm[1][j] + mm[2][i]*mm[2][j];

    float V[3][3] = {{1,0,0},{0,1,0},{0,0,1}};
    #pragma unroll
    for (int sweep = 0; sweep < 5; ++sweep) {
        jrot(Am, V, 0, 1);
        jrot(Am, V, 0, 2);
        jrot(Am, V, 1, 2);
    }
    float lam0 = Am[0][0], lam1 = Am[1][1], lam2 = Am[2][2];
    if (lam0 < lam1) { float tl=lam0; lam0=lam1; lam1=tl;
        #pragma unroll
        for (int i=0;i<3;++i){float tv=V[i][0];V[i][0]=V[i][1];V[i][1]=tv;} }
    if (lam0 < lam2) { float tl=lam0; lam0=lam2; lam2=tl;
        #pragma unroll
        for (int i=0;i<3;++i){float tv=V[i][0];V[i][0]=V[i][2];V[i][2]=tv;} }
    if (lam1 < lam2) { float tl=lam1; lam1=lam2; lam2=tl;
        #pragma unroll
        for (int i=0;i<3;++i){float tv=V[i][1];V[i][1]=V[i][2];V[i][2]=tv;} }

    float det =
          V[0][0]*(V[1][1]*V[2][2]-V[1][2]*V[2][1])
        - V[0][1]*(V[1][0]*V[2][2]-V[1][2]*V[2][0])
        + V[0][2]*(V[1][0]*V[2][1]-V[1][1]*V[2][0]);
    if (det < 0.f) { V[0][2] = -V[0][2]; V[1][2] = -V[1][2]; V[2][2] = -V[2][2]; }

    float u0[3], u1[3], u2[3];
    #pragma unroll
    for (int i = 0; i < 3; ++i)
        u0[i] = mm[i][0]*V[0][0] + mm[i][1]*V[1][0] + mm[i][2]*V[2][0];
    float nn0 = 1.f / sqrtf(u0[0]*u0[0] + u0[1]*u0[1] + u0[2]*u0[2] + 1e-30f);
    u0[0]*=nn0; u0[1]*=nn0; u0[2]*=nn0;
    #pragma unroll
    for (int i = 0; i < 3; ++i)
        u1[i] = mm[i][0]*V[0][1] + mm[i][1]*V[1][1] + mm[i][2]*V[2][1];
    float d01 = u0[0]*u1[0] + u0[1]*u1[1] + u0[2]*u1[2];
    u1[0]-=d01*u0[0]; u1[1]-=d01*u0[1]; u1[2]-=d01*u0[2];
    float nn1 = 1.f / sqrtf(u1[0]*u1[0] + u1[1]*u1[1] + u1[2]*u1[2] + 1e-30f);
    u1[0]*=nn1; u1[1]*=nn1; u1[2]*=nn1;
    u2[0] = u0[1]*u1[2] - u0[2]*u1[1];
    u2[1] = u0[2]*u1[0] - u0[0]*u1[2];
    u2[2] = u0[0]*u1[1] - u0[1]*u1[0];

    float* op = out + row * 12;
    #pragma unroll
    for (int i = 0; i < 3; ++i) {
        #pragma unroll
        for (int j = 0; j < 3; ++j)
            op[i*4 + j] = u0[i]*V[j][0] + u1[i]*V[j][1] + u2[i]*V[j][2];
        op[i*4 + 3] = y[9 + i];
    }
}

// ---------------------------------------------------------------------------
extern "C" void kernel_launch(void* const* d_in, const int* in_sizes, int n_in,
                              void* d_out, int out_size, void* d_ws, size_t ws_size,
                              hipStream_t stream)
{
    (void)in_sizes; (void)n_in; (void)out_size; (void)ws_size;

    const float* x   = (const float*)d_in[0];
    const float* W1  = (const float*)d_in[1];
    const float* b1  = (const float*)d_in[2];
    const float* g1  = (const float*)d_in[3];
    const float* be1 = (const float*)d_in[4];
    const float* W2  = (const float*)d_in[5];
    const float* b2  = (const float*)d_in[6];
    const float* g2  = (const float*)d_in[7];
    const float* be2 = (const float*)d_in[8];
    const float* W3  = (const float*)d_in[9];
    const float* b3  = (const float*)d_in[10];
    float* out = (float*)d_out;

    char* ws = (char*)d_ws;
    size_t off = 0;
    auto take = [&](size_t bytes) -> void* {
        void* p = ws + off;
        off += (bytes + 255) & ~(size_t)255;
        return p;
    };
    _Float16* w1h = (_Float16*)take((size_t)H1N * D_IN * 2);
    _Float16* w1l = (_Float16*)take((size_t)H1N * D_IN * 2);
    _Float16* w2h = (_Float16*)take((size_t)H2N * H1N * 2);
    _Float16* w2l = (_Float16*)take((size_t)H2N * H1N * 2);
    float*  h1    = (float*) take((size_t)B_ROWS * H1N * 4);
    float*  h2    = (float*) take((size_t)B_ROWS * H2N * 4);
    float2* part1 = (float2*)take((size_t)256 * H1N * 8);
    float2* part2 = (float2*)take((size_t)256 * H2N * 8);
    float2* scsh1 = (float2*)take((size_t)H1N * 8);
    float2* scsh2 = (float2*)take((size_t)H2N * 8);

    splitw_t<<<dim3((D_IN/64) * (H1N/64)), dim3(256), 0, stream>>>(W1, w1h, w1l, D_IN, H1N);
    splitw_t<<<dim3((H1N/64) * (H2N/64)), dim3(256), 0, stream>>>(W2, w2h, w2l, H1N, H2N);

    gemm_fused<D_IN, 2, false><<<dim3(512), dim3(512), 0, stream>>>(
        x, w1h, w1l, b1, nullptr, h1, part1);
    reduce_stats_g<<<dim3(2), dim3(256), 0, stream>>>(part1, 256, H1N, g1, be1, scsh1);

    gemm_fused<H1N, 1, true><<<dim3(256), dim3(512), 0, stream>>>(
        h1, w2h, w2l, b2, scsh1, h2, part2);
    reduce_stats_g<<<dim3(1), dim3(256), 0, stream>>>(part2, 256, H2N, g2, be2, scsh2);

    head_svd<<<dim3(B_ROWS / 256), dim3(256), 0, stream>>>(h2, scsh2, W3, b3, out);
}

// Round 10
// 437.010 us; speedup vs baseline: 1.5215x; 1.0210x over previous
//
#include <hip/hip_runtime.h>

#define B_ROWS 65536
#define D_IN   1024
#define H1N    512
#define H2N    256

typedef _Float16 half8  __attribute__((ext_vector_type(8)));
typedef __fp16   fp16x2 __attribute__((ext_vector_type(2)));
typedef float    f32x4v __attribute__((ext_vector_type(4)));

#define GLOAD_LDS16(gp, lp) \
    __builtin_amdgcn_global_load_lds((const __attribute__((address_space(1))) void*)(gp), \
                                     (__attribute__((address_space(3))) void*)(lp), 16, 0, 0)

// ---------------------------------------------------------------------------
// Tiled transpose+split: W [Kd][Nd] fp32 -> wh/wl [Nd][Kd] fp16 hi/lo.
// ---------------------------------------------------------------------------
__global__ __launch_bounds__(256)
void splitw_t(const float* __restrict__ W, _Float16* __restrict__ wh,
              _Float16* __restrict__ wl, int Kd, int Nd)
{
    __shared__ float tile[64][65];
    const int t = threadIdx.x;
    const int ntn = Nd >> 6;
    const int k0 = (blockIdx.x / ntn) << 6;
    const int n0 = (blockIdx.x % ntn) << 6;

    {
        int r = t >> 4, c4 = (t & 15) << 2;
        #pragma unroll
        for (int i = 0; i < 4; ++i) {
            float4 v = *(const float4*)(W + (size_t)(k0 + r + i * 16) * Nd + n0 + c4);
            tile[r + i*16][c4+0] = v.x; tile[r + i*16][c4+1] = v.y;
            tile[r + i*16][c4+2] = v.z; tile[r + i*16][c4+3] = v.w;
        }
    }
    __syncthreads();
    {
        int n = t >> 2, kc = (t & 3) << 4;
        union { fp16x2 h2[8]; half8 h8[2]; } H, L;
        #pragma unroll
        for (int i = 0; i < 8; ++i) {
            float v0 = tile[kc + 2*i][n], v1 = tile[kc + 2*i + 1][n];
            float h0 = __int_as_float(__float_as_int(v0) & 0xFFFFE000);
            float h1 = __int_as_float(__float_as_int(v1) & 0xFFFFE000);
            H.h2[i] = __builtin_amdgcn_cvt_pkrtz(h0, h1);
            L.h2[i] = __builtin_amdgcn_cvt_pkrtz(v0 - h0, v1 - h1);
        }
        _Float16* ph = wh + (size_t)(n0 + n) * Kd + k0 + kc;
        _Float16* pl = wl + (size_t)(n0 + n) * Kd + k0 + kc;
        *(half8*)ph = H.h8[0]; *(half8*)(ph + 8) = H.h8[1];
        *(half8*)pl = L.h8[0]; *(half8*)(pl + 8) = L.h8[1];
    }
}

// ---------------------------------------------------------------------------
// Split-fp16 GEMM: r4 dataflow + counted-vmcnt sync (T3+T4+T5).
// 256x256 tile, BK=32, 8 waves (2x4), wave tile 128x64, mfma 16x16x32 f16,
// 3 products (hh, hl, lh). A reg-staged, split (+BN+ReLU) at STAGE time into
// fp16 hi/lo LDS planes; B hi/lo via global_load_lds (4/wave/step).
// Per K-step: issue 8 loads -> vmcnt(8) -> barrier -> dsread+MFMA ->
// proc_write -> lgkmcnt(0) -> barrier. Prefetch loads stay in flight
// across barriers (no drain-0 in the loop).
// ---------------------------------------------------------------------------
template<int K, int NB, bool BNRELU>
__global__ __launch_bounds__(512, 2)
void gemm_fused(const float* __restrict__ Ain, const _Float16* __restrict__ Bth,
                const _Float16* __restrict__ Btl, const float* __restrict__ bias,
                const float2* __restrict__ scsh, float* __restrict__ Cout,
                float2* __restrict__ statp)
{
    constexpr int N  = NB * 256;
    constexpr int NS = K / 32;
    __shared__ alignas(16) char smb[131072 + 4096];
    const int AH0 = 0,     AH1 = 16384, AL0 = 32768, AL1 = 49152;
    const int BH0 = 65536, BH1 = 81920, BL0 = 98304, BL1 = 114688;
    float2* scl = (float2*)(smb + 131072);

    const int tid = threadIdx.x;
    const int l = tid & 63;
    const int w = tid >> 6;
    const int wr = w >> 2, wc = w & 3;

    const int bid = blockIdx.x;
    constexpr int CPX = 32 * NB;
    const int L  = (bid & 7) * CPX + (bid >> 3);      // bijective XCD swizzle
    const int mb = L / NB, nb = L % NB;
    const int m0 = mb << 8, n0 = nb << 8;

    const int ar = tid >> 1, ch = tid & 1;

    float4 rga[4];
    auto load_regs = [&](int ks) {                    // 4 vmcnt ops
        const float4* p = (const float4*)(Ain + (size_t)(m0 + ar) * K + ks * 32 + ch * 16);
        rga[0] = p[0]; rga[1] = p[1]; rga[2] = p[2]; rga[3] = p[3];
    };

    auto stageB = [&](int buf, int ks) {              // 4 vmcnt ops
        #pragma unroll
        for (int i = 0; i < 2; ++i) {
            int rbase = (w * 2 + i) * 16;
            int r = rbase + (l >> 2);
            int c = (l & 3) ^ ((r >> 1) & 3);
            const _Float16* gh = Bth + (size_t)(n0 + r) * K + ks * 32 + c * 8;
            const _Float16* gl = Btl + (size_t)(n0 + r) * K + ks * 32 + c * 8;
            GLOAD_LDS16(gh, smb + (buf ? BH1 : BH0) + rbase * 64);
            GLOAD_LDS16(gl, smb + (buf ? BL1 : BL0) + rbase * 64);
        }
    };

    auto proc_write = [&](int buf, int ks) {
        float v[16];
        #pragma unroll
        for (int p = 0; p < 4; ++p) {
            v[p*4+0] = rga[p].x; v[p*4+1] = rga[p].y;
            v[p*4+2] = rga[p].z; v[p*4+3] = rga[p].w;
        }
        if constexpr (BNRELU) {
            const float2* sp = scl + ks * 32 + ch * 16;   // global k indexing
            #pragma unroll
            for (int i = 0; i < 16; ++i) {
                float2 s2 = sp[i];
                v[i] = fmaxf(fmaf(v[i], s2.x, s2.y), 0.f);
            }
        }
        union { fp16x2 h2[4]; half8 h8; } H[2], Lo[2];
        #pragma unroll
        for (int hb = 0; hb < 2; ++hb) {
            #pragma unroll
            for (int i = 0; i < 4; ++i) {
                float a0 = v[hb*8 + 2*i], a1 = v[hb*8 + 2*i + 1];
                float h0 = __int_as_float(__float_as_int(a0) & 0xFFFFE000);
                float h1 = __int_as_float(__float_as_int(a1) & 0xFFFFE000);
                H[hb].h2[i]  = __builtin_amdgcn_cvt_pkrtz(h0, h1);
                Lo[hb].h2[i] = __builtin_amdgcn_cvt_pkrtz(a0 - h0, a1 - h1);
            }
        }
        char* bhp = smb + (buf ? AH1 : AH0) + ar * 64;
        char* blp = smb + (buf ? AL1 : AL0) + ar * 64;
        int sw = (ar >> 1) & 3;
        *(half8*)(bhp + (((ch*2)     ^ sw) * 16)) = H[0].h8;
        *(half8*)(bhp + (((ch*2 + 1) ^ sw) * 16)) = H[1].h8;
        *(half8*)(blp + (((ch*2)     ^ sw) * 16)) = Lo[0].h8;
        *(half8*)(blp + (((ch*2 + 1) ^ sw) * 16)) = Lo[1].h8;
    };

    // ---- prologue: scl + step-0 staging, one-time full drain
    if constexpr (BNRELU) {
        for (int i = tid; i < K; i += 512) scl[i] = scsh[i];
    }
    (void)scsh;
    load_regs(0);
    stageB(0, 0);
    __syncthreads();              // scl + B(0) landed/visible (one-time drain)
    proc_write(0, 0);
    __syncthreads();              // A(0) planes visible

    f32x4v acc[8][4] = {};
    for (int ks = 0; ks < NS; ++ks) {
        const int buf = ks & 1;
        if (ks < NS - 1) {
            load_regs(ks + 1);                           // 4 reg loads
            stageB(buf ^ 1, ks + 1);                     // 4 lds loads
            asm volatile("s_waitcnt vmcnt(8)" ::: "memory");  // stageB(ks) landed
        } else {
            asm volatile("s_waitcnt vmcnt(0)" ::: "memory");
        }
        __builtin_amdgcn_s_barrier();                    // buf fully ready
        asm volatile("" ::: "memory");

        const char* pah = smb + (buf ? AH1 : AH0);
        const char* pal = smb + (buf ? AL1 : AL0);
        const char* pbh = smb + (buf ? BH1 : BH0);
        const char* pbl = smb + (buf ? BL1 : BL0);

        half8 bh[4], bl[4];
        #pragma unroll
        for (int n = 0; n < 4; ++n) {
            int r = wc * 64 + n * 16 + (l & 15);
            int c = (l >> 4) ^ ((r >> 1) & 3);
            bh[n] = *(const half8*)(pbh + r * 64 + c * 16);
            bl[n] = *(const half8*)(pbl + r * 64 + c * 16);
        }
        #pragma unroll
        for (int mh = 0; mh < 2; ++mh) {
            half8 ah[4], al[4];
            #pragma unroll
            for (int mm = 0; mm < 4; ++mm) {
                int r = wr * 128 + (mh * 4 + mm) * 16 + (l & 15);
                int c = (l >> 4) ^ ((r >> 1) & 3);
                ah[mm] = *(const half8*)(pah + r * 64 + c * 16);
                al[mm] = *(const half8*)(pal + r * 64 + c * 16);
            }
            __builtin_amdgcn_s_setprio(1);
            #pragma unroll
            for (int mm = 0; mm < 4; ++mm) {
                #pragma unroll
                for (int n = 0; n < 4; ++n) {
                    f32x4v t = acc[mh * 4 + mm][n];
                    t = __builtin_amdgcn_mfma_f32_16x16x32_f16(ah[mm], bh[n], t, 0, 0, 0);
                    t = __builtin_amdgcn_mfma_f32_16x16x32_f16(ah[mm], bl[n], t, 0, 0, 0);
                    t = __builtin_amdgcn_mfma_f32_16x16x32_f16(al[mm], bh[n], t, 0, 0, 0);
                    acc[mh * 4 + mm][n] = t;
                }
            }
            __builtin_amdgcn_s_setprio(0);
        }

        if (ks < NS - 1) proc_write(buf ^ 1, ks + 1);    // compiler waits vmcnt(4) for rga
        asm volatile("s_waitcnt lgkmcnt(0)" ::: "memory");   // own ds ops drained
        __builtin_amdgcn_s_barrier();                    // reads of buf done
        asm volatile("" ::: "memory");
    }

    // ---- epilogue: bias add, C store, fused column stats
    float bv[4], s[4], q[4];
    #pragma unroll
    for (int n = 0; n < 4; ++n) {
        bv[n] = bias[n0 + wc * 64 + n * 16 + (l & 15)];
        s[n] = 0.f; q[n] = 0.f;
    }
    #pragma unroll
    for (int m = 0; m < 8; ++m) {
        int row = m0 + wr * 128 + m * 16 + ((l >> 4) << 2);
        #pragma unroll
        for (int n = 0; n < 4; ++n) {
            int col = n0 + wc * 64 + n * 16 + (l & 15);
            float* cp = Cout + (size_t)row * N + col;
            #pragma unroll
            for (int j = 0; j < 4; ++j) {
                float v = acc[m][n][j] + bv[n];
                cp[(size_t)j * N] = v;
                s[n] += v; q[n] += v * v;
            }
        }
    }
    #pragma unroll
    for (int n = 0; n < 4; ++n) {
        s[n] += __shfl_xor(s[n], 16); s[n] += __shfl_xor(s[n], 32);
        q[n] += __shfl_xor(q[n], 16); q[n] += __shfl_xor(q[n], 32);
    }
    __syncthreads();
    float2* red = (float2*)smb;
    if (wr == 1 && l < 16) {
        #pragma unroll
        for (int n = 0; n < 4; ++n) red[(wc * 4 + n) * 16 + l] = make_float2(s[n], q[n]);
    }
    __syncthreads();
    if (wr == 0 && l < 16) {
        #pragma unroll
        for (int n = 0; n < 4; ++n) {
            float2 o = red[(wc * 4 + n) * 16 + l];
            int col = n0 + wc * 64 + n * 16 + l;
            statp[(size_t)mb * N + col] = make_float2(s[n] + o.x, q[n] + o.y);
        }
    }
}

// ---------------------------------------------------------------------------
// Column-stat reduce: mean/var -> (scale, shift)
// ---------------------------------------------------------------------------
__global__ void reduce_stats_g(const float2* __restrict__ part, int nparts, int ncols,
                               const float* __restrict__ g, const float* __restrict__ be,
                               float2* __restrict__ scsh)
{
    int c = blockIdx.x * blockDim.x + threadIdx.x;
    if (c >= ncols) return;
    float s = 0.f, q = 0.f;
    for (int p = 0; p < nparts; ++p) {
        float2 v = part[(size_t)p * ncols + c];
        s += v.x; q += v.y;
    }
    const float invB = 1.f / 65536.f;
    float mu = s * invB, var = q * invB - mu * mu;
    float sc = g[c] * rsqrtf(var + 1e-5f);
    scsh[c] = make_float2(sc, be[c] - mu * sc);
}

// ---------------------------------------------------------------------------
// Head: y = relu(bn(h2)) @ W3 + b3, then per-row SO(3) projection (Jacobi).
// ---------------------------------------------------------------------------
__device__ __forceinline__ void jrot(float A[3][3], float V[3][3], int p, int q)
{
    float apq = A[p][q];
    float tau = A[q][q] - A[p][p];
    float a2  = 2.f * apq;
    float Dd  = fabsf(tau) + sqrtf(tau * tau + a2 * a2) + 1e-38f;
    float tt  = copysignf(1.f, tau) * a2 / Dd;
    float c   = 1.f / sqrtf(1.f + tt * tt);
    float s   = tt * c;
    int   r   = 3 - p - q;
    float App = A[p][p], Aqq = A[q][q];
    A[p][p] = App - tt * apq;
    A[q][q] = Aqq + tt * apq;
    A[p][q] = 0.f; A[q][p] = 0.f;
    float Arp = A[r][p], Arq = A[r][q];
    A[r][p] = c * Arp - s * Arq; A[p][r] = A[r][p];
    A[r][q] = s * Arp + c * Arq; A[q][r] = A[r][q];
    #pragma unroll
    for (int i = 0; i < 3; ++i) {
        float vp = V[i][p], vq = V[i][q];
        V[i][p] = c * vp - s * vq;
        V[i][q] = s * vp + c * vq;
    }
}

__global__ __launch_bounds__(256)
void head_svd(const float* __restrict__ H2, const float2* __restrict__ scsh2,
              const float* __restrict__ W3, const float* __restrict__ b3,
              float* __restrict__ out)
{
    __shared__ alignas(16) float  w3s[H2N * 12];
    __shared__ alignas(16) float2 ss[H2N];
    __shared__ float b3s[12];
    __shared__ alignas(16) float tile[64][257];

    const int t = threadIdx.x;
    for (int i = t; i < H2N * 12; i += 256) w3s[i] = W3[i];
    ss[t] = scsh2[t];
    if (t < 12) b3s[t] = b3[t];
    __syncthreads();

    const size_t rbase = (size_t)blockIdx.x * 256;
    const size_t row = rbase + t;
    float y[12];
    #pragma unroll
    for (int o = 0; o < 12; ++o) y[o] = b3s[o];

    for (int kc = 0; kc < 4; ++kc) {
        #pragma unroll
        for (int i = 0; i < 16; ++i) {
            int rr = (t >> 4) + i * 16;
            int k4 = (t & 15) * 4;
            float4 v = *(const float4*)(H2 + (rbase + rr) * H2N + kc * 64 + k4);
            float2 sA = ss[kc*64 + k4 + 0];
            float2 sB = ss[kc*64 + k4 + 1];
            float2 sC = ss[kc*64 + k4 + 2];
            float2 sD = ss[kc*64 + k4 + 3];
            tile[k4+0][rr] = fmaxf(fmaf(v.x, sA.x, sA.y), 0.f);
            tile[k4+1][rr] = fmaxf(fmaf(v.y, sB.x, sB.y), 0.f);
            tile[k4+2][rr] = fmaxf(fmaf(v.z, sC.x, sC.y), 0.f);
            tile[k4+3][rr] = fmaxf(fmaf(v.w, sD.x, sD.y), 0.f);
        }
        __syncthreads();
        #pragma unroll 4
        for (int k = 0; k < 64; ++k) {
            float v = tile[k][t];
            const float* wp = &w3s[(kc * 64 + k) * 12];
            #pragma unroll
            for (int o = 0; o < 12; ++o) y[o] = fmaf(v, wp[o], y[o]);
        }
        __syncthreads();
    }

    float mm[3][3];
    #pragma unroll
    for (int i = 0; i < 3; ++i)
        #pragma unroll
        for (int j = 0; j < 3; ++j) mm[i][j] = y[i * 3 + j];

    float Am[3][3];
    #pragma unroll
    for (int i = 0; i < 3; ++i)
        #pragma unroll
        for (int j = 0; j < 3; ++j)
            Am[i][j] = mm[0][i]*mm[0][j] + mm[1][i]*mm[1][j] + mm[2][i]*mm[2][j];

    float V[3][3] = {{1,0,0},{0,1,0},{0,0,1}};
    #pragma unroll
    for (int sweep = 0; sweep < 5; ++sweep) {
        jrot(Am, V, 0, 1);
        jrot(Am, V, 0, 2);
        jrot(Am, V, 1, 2);
    }
    float lam0 = Am[0][0], lam1 = Am[1][1], lam2 = Am[2][2];
    if (lam0 < lam1) { float tl=lam0; lam0=lam1; lam1=tl;
        #pragma unroll
        for (int i=0;i<3;++i){float tv=V[i][0];V[i][0]=V[i][1];V[i][1]=tv;} }
    if (lam0 < lam2) { float tl=lam0; lam0=lam2; lam2=tl;
        #pragma unroll
        for (int i=0;i<3;++i){float tv=V[i][0];V[i][0]=V[i][2];V[i][2]=tv;} }
    if (lam1 < lam2) { float tl=lam1; lam1=lam2; lam2=tl;
        #pragma unroll
        for (int i=0;i<3;++i){float tv=V[i][1];V[i][1]=V[i][2];V[i][2]=tv;} }

    float det =
          V[0][0]*(V[1][1]*V[2][2]-V[1][2]*V[2][1])
        - V[0][1]*(V[1][0]*V[2][2]-V[1][2]*V[2][0])
        + V[0][2]*(V[1][0]*V[2][1]-V[1][1]*V[2][0]);
    if (det < 0.f) { V[0][2] = -V[0][2]; V[1][2] = -V[1][2]; V[2][2] = -V[2][2]; }

    float u0[3], u1[3], u2[3];
    #pragma unroll
    for (int i = 0; i < 3; ++i)
        u0[i] = mm[i][0]*V[0][0] + mm[i][1]*V[1][0] + mm[i][2]*V[2][0];
    float nn0 = 1.f / sqrtf(u0[0]*u0[0] + u0[1]*u0[1] + u0[2]*u0[2] + 1e-30f);
    u0[0]*=nn0; u0[1]*=nn0; u0[2]*=nn0;
    #pragma unroll
    for (int i = 0; i < 3; ++i)
        u1[i] = mm[i][0]*V[0][1] + mm[i][1]*V[1][1] + mm[i][2]*V[2][1];
    float d01 = u0[0]*u1[0] + u0[1]*u1[1] + u0[2]*u1[2];
    u1[0]-=d01*u0[0]; u1[1]-=d01*u0[1]; u1[2]-=d01*u0[2];
    float nn1 = 1.f / sqrtf(u1[0]*u1[0] + u1[1]*u1[1] + u1[2]*u1[2] + 1e-30f);
    u1[0]*=nn1; u1[1]*=nn1; u1[2]*=nn1;
    u2[0] = u0[1]*u1[2] - u0[2]*u1[1];
    u2[1] = u0[2]*u1[0] - u0[0]*u1[2];
    u2[2] = u0[0]*u1[1] - u0[1]*u1[0];

    float* op = out + row * 12;
    #pragma unroll
    for (int i = 0; i < 3; ++i) {
        #pragma unroll
        for (int j = 0; j < 3; ++j)
            op[i*4 + j] = u0[i]*V[j][0] + u1[i]*V[j][1] + u2[i]*V[j][2];
        op[i*4 + 3] = y[9 + i];
    }
}

// ---------------------------------------------------------------------------
extern "C" void kernel_launch(void* const* d_in, const int* in_sizes, int n_in,
                              void* d_out, int out_size, void* d_ws, size_t ws_size,
                              hipStream_t stream)
{
    (void)in_sizes; (void)n_in; (void)out_size; (void)ws_size;

    const float* x   = (const float*)d_in[0];
    const float* W1  = (const float*)d_in[1];
    const float* b1  = (const float*)d_in[2];
    const float* g1  = (const float*)d_in[3];
    const float* be1 = (const float*)d_in[4];
    const float* W2  = (const float*)d_in[5];
    const float* b2  = (const float*)d_in[6];
    const float* g2  = (const float*)d_in[7];
    const float* be2 = (const float*)d_in[8];
    const float* W3  = (const float*)d_in[9];
    const float* b3  = (const float*)d_in[10];
    float* out = (float*)d_out;

    char* ws = (char*)d_ws;
    size_t off = 0;
    auto take = [&](size_t bytes) -> void* {
        void* p = ws + off;
        off += (bytes + 255) & ~(size_t)255;
        return p;
    };
    _Float16* w1h = (_Float16*)take((size_t)H1N * D_IN * 2);
    _Float16* w1l = (_Float16*)take((size_t)H1N * D_IN * 2);
    _Float16* w2h = (_Float16*)take((size_t)H2N * H1N * 2);
    _Float16* w2l = (_Float16*)take((size_t)H2N * H1N * 2);
    float*  h1    = (float*) take((size_t)B_ROWS * H1N * 4);
    float*  h2    = (float*) take((size_t)B_ROWS * H2N * 4);
    float2* part1 = (float2*)take((size_t)256 * H1N * 8);
    float2* part2 = (float2*)take((size_t)256 * H2N * 8);
    float2* scsh1 = (float2*)take((size_t)H1N * 8);
    float2* scsh2 = (float2*)take((size_t)H2N * 8);

    splitw_t<<<dim3((D_IN/64) * (H1N/64)), dim3(256), 0, stream>>>(W1, w1h, w1l, D_IN, H1N);
    splitw_t<<<dim3((H1N/64) * (H2N/64)), dim3(256), 0, stream>>>(W2, w2h, w2l, H1N, H2N);

    gemm_fused<D_IN, 2, false><<<dim3(512), dim3(512), 0, stream>>>(
        x, w1h, w1l, b1, nullptr, h1, part1);
    reduce_stats_g<<<dim3(2), dim3(256), 0, stream>>>(part1, 256, H1N, g1, be1, scsh1);

    gemm_fused<H1N, 1, true><<<dim3(256), dim3(512), 0, stream>>>(
        h1, w2h, w2l, b2, scsh1, h2, part2);
    reduce_stats_g<<<dim3(1), dim3(256), 0, stream>>>(part2, 256, H2N, g2, be2, scsh2);

    head_svd<<<dim3(B_ROWS / 256), dim3(256), 0, stream>>>(h2, scsh2, W3, b3, out);
}

// Round 11
// 417.227 us; speedup vs baseline: 1.5936x; 1.0474x over previous
//
#include <hip/hip_runtime.h>

#define B_ROWS 65536
#define D_IN   1024
#define H1N    512
#define H2N    256

typedef _Float16 half8  __attribute__((ext_vector_type(8)));
typedef __fp16   fp16x2 __attribute__((ext_vector_type(2)));
typedef float    f32x4v __attribute__((ext_vector_type(4)));

#define GLOAD_LDS16(gp, lp) \
    __builtin_amdgcn_global_load_lds((const __attribute__((address_space(1))) void*)(gp), \
                                     (__attribute__((address_space(3))) void*)(lp), 16, 0, 0)

// ---------------------------------------------------------------------------
// Tiled transpose+split: W [Kd][Nd] fp32 -> wh/wl [Nd][Kd] fp16 hi/lo.
// ---------------------------------------------------------------------------
__global__ __launch_bounds__(256)
void splitw_t(const float* __restrict__ W, _Float16* __restrict__ wh,
              _Float16* __restrict__ wl, int Kd, int Nd)
{
    __shared__ float tile[64][65];
    const int t = threadIdx.x;
    const int ntn = Nd >> 6;
    const int k0 = (blockIdx.x / ntn) << 6;
    const int n0 = (blockIdx.x % ntn) << 6;

    {
        int r = t >> 4, c4 = (t & 15) << 2;
        #pragma unroll
        for (int i = 0; i < 4; ++i) {
            float4 v = *(const float4*)(W + (size_t)(k0 + r + i * 16) * Nd + n0 + c4);
            tile[r + i*16][c4+0] = v.x; tile[r + i*16][c4+1] = v.y;
            tile[r + i*16][c4+2] = v.z; tile[r + i*16][c4+3] = v.w;
        }
    }
    __syncthreads();
    {
        int n = t >> 2, kc = (t & 3) << 4;
        union { fp16x2 h2[8]; half8 h8[2]; } H, L;
        #pragma unroll
        for (int i = 0; i < 8; ++i) {
            float v0 = tile[kc + 2*i][n], v1 = tile[kc + 2*i + 1][n];
            float h0 = __int_as_float(__float_as_int(v0) & 0xFFFFE000);
            float h1 = __int_as_float(__float_as_int(v1) & 0xFFFFE000);
            H.h2[i] = __builtin_amdgcn_cvt_pkrtz(h0, h1);
            L.h2[i] = __builtin_amdgcn_cvt_pkrtz(v0 - h0, v1 - h1);
        }
        _Float16* ph = wh + (size_t)(n0 + n) * Kd + k0 + kc;
        _Float16* pl = wl + (size_t)(n0 + n) * Kd + k0 + kc;
        *(half8*)ph = H.h8[0]; *(half8*)(ph + 8) = H.h8[1];
        *(half8*)pl = L.h8[0]; *(half8*)(pl + 8) = L.h8[1];
    }
}

// ---------------------------------------------------------------------------
// Split-fp16 GEMM, r4 sync structure, 16 waves (1024 thr) for 4 waves/SIMD.
// 256x256 tile, BK=32, wave grid 4x4, wave tile 64x64, mfma 16x16x32 f16,
// 3 products (hh, hl, lh). A reg-staged, split (+BN+ReLU) at stage time into
// fp16 hi/lo LDS planes; B hi/lo via global_load_lds (1 per wave per plane).
// One drain-0 __syncthreads per K-step (proven best vs counted variants).
// ---------------------------------------------------------------------------
template<int K, int NB, bool BNRELU>
__global__ __launch_bounds__(1024, 4)
void gemm_fused(const float* __restrict__ Ain, const _Float16* __restrict__ Bth,
                const _Float16* __restrict__ Btl, const float* __restrict__ bias,
                const float2* __restrict__ scsh, float* __restrict__ Cout,
                float2* __restrict__ statp)
{
    constexpr int N  = NB * 256;
    constexpr int NS = K / 32;
    __shared__ alignas(16) char smb[131072 + 4096];
    const int AH0 = 0,     AH1 = 16384, AL0 = 32768, AL1 = 49152;
    const int BH0 = 65536, BH1 = 81920, BL0 = 98304, BL1 = 114688;
    float2* scl = (float2*)(smb + 131072);

    const int tid = threadIdx.x;
    const int l = tid & 63;
    const int w = tid >> 6;                           // 0..15
    const int wr = w >> 2, wc = w & 3;                // 4x4 wave grid

    const int bid = blockIdx.x;
    constexpr int CPX = 32 * NB;
    const int L  = (bid & 7) * CPX + (bid >> 3);      // bijective XCD swizzle
    const int mb = L / NB, nb = L % NB;
    const int m0 = mb << 8, n0 = nb << 8;

    const int ar = tid >> 2, ch = tid & 3;            // row 0..255, k-chunk 0..3

    float4 rga[2];
    auto load_regs = [&](int ks) {                    // 8 floats/thread
        const float4* p = (const float4*)(Ain + (size_t)(m0 + ar) * K + ks * 32 + ch * 8);
        rga[0] = p[0]; rga[1] = p[1];
    };

    auto stageB = [&](int buf, int ks) {              // 1 gload/wave/plane
        int rbase = w * 16;
        int r = rbase + (l >> 2);
        int c = (l & 3) ^ ((r >> 1) & 3);
        const _Float16* gh = Bth + (size_t)(n0 + r) * K + ks * 32 + c * 8;
        const _Float16* gl = Btl + (size_t)(n0 + r) * K + ks * 32 + c * 8;
        GLOAD_LDS16(gh, smb + (buf ? BH1 : BH0) + rbase * 64);
        GLOAD_LDS16(gl, smb + (buf ? BL1 : BL0) + rbase * 64);
    };

    auto proc_write = [&](int buf, int ks) {
        float v[8] = {rga[0].x, rga[0].y, rga[0].z, rga[0].w,
                      rga[1].x, rga[1].y, rga[1].z, rga[1].w};
        if constexpr (BNRELU) {
            const float2* sp = scl + ks * 32 + ch * 8;     // global k indexing
            #pragma unroll
            for (int i = 0; i < 8; ++i) {
                float2 s2 = sp[i];
                v[i] = fmaxf(fmaf(v[i], s2.x, s2.y), 0.f);
            }
        }
        union { fp16x2 h2[4]; half8 h8; } H, Lo;
        #pragma unroll
        for (int i = 0; i < 4; ++i) {
            float a0 = v[2*i], a1 = v[2*i + 1];
            float h0 = __int_as_float(__float_as_int(a0) & 0xFFFFE000);
            float h1 = __int_as_float(__float_as_int(a1) & 0xFFFFE000);
            H.h2[i]  = __builtin_amdgcn_cvt_pkrtz(h0, h1);
            Lo.h2[i] = __builtin_amdgcn_cvt_pkrtz(a0 - h0, a1 - h1);
        }
        int sw = (ar >> 1) & 3;
        *(half8*)(smb + (buf ? AH1 : AH0) + ar * 64 + ((ch ^ sw) * 16)) = H.h8;
        *(half8*)(smb + (buf ? AL1 : AL0) + ar * 64 + ((ch ^ sw) * 16)) = Lo.h8;
    };

    // ---- prologue
    if constexpr (BNRELU) {
        for (int i = tid; i < K; i += 1024) scl[i] = scsh[i];
    }
    (void)scsh;
    load_regs(0);
    stageB(0, 0);
    __syncthreads();              // scl + B(0) landed
    proc_write(0, 0);
    __syncthreads();              // A(0) planes visible

    f32x4v acc[4][4] = {};
    for (int ks = 0; ks < NS; ++ks) {
        const int buf = ks & 1;
        if (ks < NS - 1) { load_regs(ks + 1); stageB(buf ^ 1, ks + 1); }

        const char* pah = smb + (buf ? AH1 : AH0);
        const char* pal = smb + (buf ? AL1 : AL0);
        const char* pbh = smb + (buf ? BH1 : BH0);
        const char* pbl = smb + (buf ? BL1 : BL0);

        half8 bh[4], bl[4], ah[4], al[4];
        #pragma unroll
        for (int n = 0; n < 4; ++n) {
            int r = wc * 64 + n * 16 + (l & 15);
            int c = (l >> 4) ^ ((r >> 1) & 3);
            bh[n] = *(const half8*)(pbh + r * 64 + c * 16);
            bl[n] = *(const half8*)(pbl + r * 64 + c * 16);
        }
        #pragma unroll
        for (int m = 0; m < 4; ++m) {
            int r = wr * 64 + m * 16 + (l & 15);
            int c = (l >> 4) ^ ((r >> 1) & 3);
            ah[m] = *(const half8*)(pah + r * 64 + c * 16);
            al[m] = *(const half8*)(pal + r * 64 + c * 16);
        }
        #pragma unroll
        for (int m = 0; m < 4; ++m) {
            #pragma unroll
            for (int n = 0; n < 4; ++n) {
                f32x4v t = acc[m][n];
                t = __builtin_amdgcn_mfma_f32_16x16x32_f16(ah[m], bh[n], t, 0, 0, 0);
                t = __builtin_amdgcn_mfma_f32_16x16x32_f16(ah[m], bl[n], t, 0, 0, 0);
                t = __builtin_amdgcn_mfma_f32_16x16x32_f16(al[m], bh[n], t, 0, 0, 0);
                acc[m][n] = t;
            }
        }
        if (ks < NS - 1) proc_write(buf ^ 1, ks + 1);
        __syncthreads();
    }

    // ---- epilogue: bias add, C store, fused column stats
    float bv[4], s[4], q[4];
    #pragma unroll
    for (int n = 0; n < 4; ++n) {
        bv[n] = bias[n0 + wc * 64 + n * 16 + (l & 15)];
        s[n] = 0.f; q[n] = 0.f;
    }
    #pragma unroll
    for (int m = 0; m < 4; ++m) {
        int row = m0 + wr * 64 + m * 16 + ((l >> 4) << 2);
        #pragma unroll
        for (int n = 0; n < 4; ++n) {
            int col = n0 + wc * 64 + n * 16 + (l & 15);
            float* cp = Cout + (size_t)row * N + col;
            #pragma unroll
            for (int j = 0; j < 4; ++j) {
                float v = acc[m][n][j] + bv[n];
                cp[(size_t)j * N] = v;
                s[n] += v; q[n] += v * v;
            }
        }
    }
    #pragma unroll
    for (int n = 0; n < 4; ++n) {
        s[n] += __shfl_xor(s[n], 16); s[n] += __shfl_xor(s[n], 32);
        q[n] += __shfl_xor(q[n], 16); q[n] += __shfl_xor(q[n], 32);
    }
    __syncthreads();
    float2* red = (float2*)smb;                       // 3 slices x 256 float2
    if (wr > 0 && l < 16) {
        #pragma unroll
        for (int n = 0; n < 4; ++n)
            red[(wr - 1) * 256 + (wc * 4 + n) * 16 + l] = make_float2(s[n], q[n]);
    }
    __syncthreads();
    if (wr == 0 && l < 16) {
        #pragma unroll
        for (int n = 0; n < 4; ++n) {
            float ts = s[n], tq = q[n];
            #pragma unroll
            for (int sl = 0; sl < 3; ++sl) {
                float2 o = red[sl * 256 + (wc * 4 + n) * 16 + l];
                ts += o.x; tq += o.y;
            }
            int col = n0 + wc * 64 + n * 16 + l;
            statp[(size_t)mb * N + col] = make_float2(ts, tq);
        }
    }
}

// ---------------------------------------------------------------------------
// Column-stat reduce: mean/var -> (scale, shift)
// ---------------------------------------------------------------------------
__global__ void reduce_stats_g(const float2* __restrict__ part, int nparts, int ncols,
                               const float* __restrict__ g, const float* __restrict__ be,
                               float2* __restrict__ scsh)
{
    int c = blockIdx.x * blockDim.x + threadIdx.x;
    if (c >= ncols) return;
    float s = 0.f, q = 0.f;
    for (int p = 0; p < nparts; ++p) {
        float2 v = part[(size_t)p * ncols + c];
        s += v.x; q += v.y;
    }
    const float invB = 1.f / 65536.f;
    float mu = s * invB, var = q * invB - mu * mu;
    float sc = g[c] * rsqrtf(var + 1e-5f);
    scsh[c] = make_float2(sc, be[c] - mu * sc);
}

// ---------------------------------------------------------------------------
// Head: y = relu(bn(h2)) @ W3 + b3, then per-row SO(3) projection (Jacobi).
// ---------------------------------------------------------------------------
__device__ __forceinline__ void jrot(float A[3][3], float V[3][3], int p, int q)
{
    float apq = A[p][q];
    float tau = A[q][q] - A[p][p];
    float a2  = 2.f * apq;
    float Dd  = fabsf(tau) + sqrtf(tau * tau + a2 * a2) + 1e-38f;
    float tt  = copysignf(1.f, tau) * a2 / Dd;
    float c   = 1.f / sqrtf(1.f + tt * tt);
    float s   = tt * c;
    int   r   = 3 - p - q;
    float App = A[p][p], Aqq = A[q][q];
    A[p][p] = App - tt * apq;
    A[q][q] = Aqq + tt * apq;
    A[p][q] = 0.f; A[q][p] = 0.f;
    float Arp = A[r][p], Arq = A[r][q];
    A[r][p] = c * Arp - s * Arq; A[p][r] = A[r][p];
    A[r][q] = s * Arp + c * Arq; A[q][r] = A[r][q];
    #pragma unroll
    for (int i = 0; i < 3; ++i) {
        float vp = V[i][p], vq = V[i][q];
        V[i][p] = c * vp - s * vq;
        V[i][q] = s * vp + c * vq;
    }
}

__global__ __launch_bounds__(256)
void head_svd(const float* __restrict__ H2, const float2* __restrict__ scsh2,
              const float* __restrict__ W3, const float* __restrict__ b3,
              float* __restrict__ out)
{
    __shared__ alignas(16) float  w3s[H2N * 12];
    __shared__ alignas(16) float2 ss[H2N];
    __shared__ float b3s[12];
    __shared__ alignas(16) float tile[64][257];

    const int t = threadIdx.x;
    for (int i = t; i < H2N * 12; i += 256) w3s[i] = W3[i];
    ss[t] = scsh2[t];
    if (t < 12) b3s[t] = b3[t];
    __syncthreads();

    const size_t rbase = (size_t)blockIdx.x * 256;
    const size_t row = rbase + t;
    float y[12];
    #pragma unroll
    for (int o = 0; o < 12; ++o) y[o] = b3s[o];

    for (int kc = 0; kc < 4; ++kc) {
        #pragma unroll
        for (int i = 0; i < 16; ++i) {
            int rr = (t >> 4) + i * 16;
            int k4 = (t & 15) * 4;
            float4 v = *(const float4*)(H2 + (rbase + rr) * H2N + kc * 64 + k4);
            float2 sA = ss[kc*64 + k4 + 0];
            float2 sB = ss[kc*64 + k4 + 1];
            float2 sC = ss[kc*64 + k4 + 2];
            float2 sD = ss[kc*64 + k4 + 3];
            tile[k4+0][rr] = fmaxf(fmaf(v.x, sA.x, sA.y), 0.f);
            tile[k4+1][rr] = fmaxf(fmaf(v.y, sB.x, sB.y), 0.f);
            tile[k4+2][rr] = fmaxf(fmaf(v.z, sC.x, sC.y), 0.f);
            tile[k4+3][rr] = fmaxf(fmaf(v.w, sD.x, sD.y), 0.f);
        }
        __syncthreads();
        #pragma unroll 4
        for (int k = 0; k < 64; ++k) {
            float v = tile[k][t];
            const float* wp = &w3s[(kc * 64 + k) * 12];
            #pragma unroll
            for (int o = 0; o < 12; ++o) y[o] = fmaf(v, wp[o], y[o]);
        }
        __syncthreads();
    }

    float mm[3][3];
    #pragma unroll
    for (int i = 0; i < 3; ++i)
        #pragma unroll
        for (int j = 0; j < 3; ++j) mm[i][j] = y[i * 3 + j];

    float Am[3][3];
    #pragma unroll
    for (int i = 0; i < 3; ++i)
        #pragma unroll
        for (int j = 0; j < 3; ++j)
            Am[i][j] = mm[0][i]*mm[0][j] + mm[1][i]*mm[1][j] + mm[2][i]*mm[2][j];

    float V[3][3] = {{1,0,0},{0,1,0},{0,0,1}};
    #pragma unroll
    for (int sweep = 0; sweep < 5; ++sweep) {
        jrot(Am, V, 0, 1);
        jrot(Am, V, 0, 2);
        jrot(Am, V, 1, 2);
    }
    float lam0 = Am[0][0], lam1 = Am[1][1], lam2 = Am[2][2];
    if (lam0 < lam1) { float tl=lam0; lam0=lam1; lam1=tl;
        #pragma unroll
        for (int i=0;i<3;++i){float tv=V[i][0];V[i][0]=V[i][1];V[i][1]=tv;} }
    if (lam0 < lam2) { float tl=lam0; lam0=lam2; lam2=tl;
        #pragma unroll
        for (int i=0;i<3;++i){float tv=V[i][0];V[i][0]=V[i][2];V[i][2]=tv;} }
    if (lam1 < lam2) { float tl=lam1; lam1=lam2; lam2=tl;
        #pragma unroll
        for (int i=0;i<3;++i){float tv=V[i][1];V[i][1]=V[i][2];V[i][2]=tv;} }

    float det =
          V[0][0]*(V[1][1]*V[2][2]-V[1][2]*V[2][1])
        - V[0][1]*(V[1][0]*V[2][2]-V[1][2]*V[2][0])
        + V[0][2]*(V[1][0]*V[2][1]-V[1][1]*V[2][0]);
    if (det < 0.f) { V[0][2] = -V[0][2]; V[1][2] = -V[1][2]; V[2][2] = -V[2][2]; }

    float u0[3], u1[3], u2[3];
    #pragma unroll
    for (int i = 0; i < 3; ++i)
        u0[i] = mm[i][0]*V[0][0] + mm[i][1]*V[1][0] + mm[i][2]*V[2][0];
    float nn0 = 1.f / sqrtf(u0[0]*u0[0] + u0[1]*u0[1] + u0[2]*u0[2] + 1e-30f);
    u0[0]*=nn0; u0[1]*=nn0; u0[2]*=nn0;
    #pragma unroll
    for (int i = 0; i < 3; ++i)
        u1[i] = mm[i][0]*V[0][1] + mm[i][1]*V[1][1] + mm[i][2]*V[2][1];
    float d01 = u0[0]*u1[0] + u0[1]*u1[1] + u0[2]*u1[2];
    u1[0]-=d01*u0[0]; u1[1]-=d01*u0[1]; u1[2]-=d01*u0[2];
    float nn1 = 1.f / sqrtf(u1[0]*u1[0] + u1[1]*u1[1] + u1[2]*u1[2] + 1e-30f);
    u1[0]*=nn1; u1[1]*=nn1; u1[2]*=nn1;
    u2[0] = u0[1]*u1[2] - u0[2]*u1[1];
    u2[1] = u0[2]*u1[0] - u0[0]*u1[2];
    u2[2] = u0[0]*u1[1] - u0[1]*u1[0];

    float* op = out + row * 12;
    #pragma unroll
    for (int i = 0; i < 3; ++i) {
        #pragma unroll
        for (int j = 0; j < 3; ++j)
            op[i*4 + j] = u0[i]*V[j][0] + u1[i]*V[j][1] + u2[i]*V[j][2];
        op[i*4 + 3] = y[9 + i];
    }
}

// ---------------------------------------------------------------------------
extern "C" void kernel_launch(void* const* d_in, const int* in_sizes, int n_in,
                              void* d_out, int out_size, void* d_ws, size_t ws_size,
                              hipStream_t stream)
{
    (void)in_sizes; (void)n_in; (void)out_size; (void)ws_size;

    const float* x   = (const float*)d_in[0];
    const float* W1  = (const float*)d_in[1];
    const float* b1  = (const float*)d_in[2];
    const float* g1  = (const float*)d_in[3];
    const float* be1 = (const float*)d_in[4];
    const float* W2  = (const float*)d_in[5];
    const float* b2  = (const float*)d_in[6];
    const float* g2  = (const float*)d_in[7];
    const float* be2 = (const float*)d_in[8];
    const float* W3  = (const float*)d_in[9];
    const float* b3  = (const float*)d_in[10];
    float* out = (float*)d_out;

    char* ws = (char*)d_ws;
    size_t off = 0;
    auto take = [&](size_t bytes) -> void* {
        void* p = ws + off;
        off += (bytes + 255) & ~(size_t)255;
        return p;
    };
    _Float16* w1h = (_Float16*)take((size_t)H1N * D_IN * 2);
    _Float16* w1l = (_Float16*)take((size_t)H1N * D_IN * 2);
    _Float16* w2h = (_Float16*)take((size_t)H2N * H1N * 2);
    _Float16* w2l = (_Float16*)take((size_t)H2N * H1N * 2);
    float*  h1    = (float*) take((size_t)B_ROWS * H1N * 4);
    float*  h2    = (float*) take((size_t)B_ROWS * H2N * 4);
    float2* part1 = (float2*)take((size_t)256 * H1N * 8);
    float2* part2 = (float2*)take((size_t)256 * H2N * 8);
    float2* scsh1 = (float2*)take((size_t)H1N * 8);
    float2* scsh2 = (float2*)take((size_t)H2N * 8);

    splitw_t<<<dim3((D_IN/64) * (H1N/64)), dim3(256), 0, stream>>>(W1, w1h, w1l, D_IN, H1N);
    splitw_t<<<dim3((H1N/64) * (H2N/64)), dim3(256), 0, stream>>>(W2, w2h, w2l, H1N, H2N);

    gemm_fused<D_IN, 2, false><<<dim3(512), dim3(1024), 0, stream>>>(
        x, w1h, w1l, b1, nullptr, h1, part1);
    reduce_stats_g<<<dim3(2), dim3(256), 0, stream>>>(part1, 256, H1N, g1, be1, scsh1);

    gemm_fused<H1N, 1, true><<<dim3(256), dim3(1024), 0, stream>>>(
        h1, w2h, w2l, b2, scsh1, h2, part2);
    reduce_stats_g<<<dim3(1), dim3(256), 0, stream>>>(part2, 256, H2N, g2, be2, scsh2);

    head_svd<<<dim3(B_ROWS / 256), dim3(256), 0, stream>>>(h2, scsh2, W3, b3, out);
}